// Round 7
// baseline (253.600 us; speedup 1.0000x reference)
//
#include <hip/hip_runtime.h>
#include <hip/hip_fp16.h>

// Problem constants (from reference): B=2, N=512, D=256, H=8, L=3
#define BB 2
#define NNq 512
#define DDm 256
#define HHh 8
#define DHh 32
#define LLn 3

static constexpr float EPSF   = 1e-4f;
static constexpr float INV2PI = 0.15915494309189535f;   // 1/(2*pi)
static constexpr float SCALE  = 0.17677669529663687f;   // 1/sqrt(32)

#if __has_builtin(__builtin_amdgcn_fractf)
#define FRACTF(x) __builtin_amdgcn_fractf(x)
#else
#define FRACTF(x) ((x) - floorf(x))
#endif
#if __has_builtin(__builtin_amdgcn_sinf)
#define SINR(x) __builtin_amdgcn_sinf(x)   // sin(2*pi*x), x in revolutions
#define COSR(x) __builtin_amdgcn_cosf(x)
#else
#define SINR(x) __sinf((x) * 6.2831853071795865f)
#define COSR(x) __cosf((x) * 6.2831853071795865f)
#endif

struct __align__(8) H4 { __half a, b, c, d; };

typedef _Float16 f16x8 __attribute__((ext_vector_type(8)));
typedef float    f32x4 __attribute__((ext_vector_type(4)));

// ---------------------------------------------------------------- boxprep
__global__ __launch_bounds__(256) void k_boxprep(const float* __restrict__ boxes,
                                                 float* __restrict__ boxp) {
    int idx = blockIdx.x * 256 + threadIdx.x;
    if (idx >= BB * NNq) return;
    float4 bx = reinterpret_cast<const float4*>(boxes)[idx];
    float cx = 0.5f * (bx.x + bx.z), cy = 0.5f * (bx.y + bx.w);
    float w = fmaxf(bx.z - bx.x, EPSF), h = fmaxf(bx.w - bx.y, EPSF);
    reinterpret_cast<float4*>(boxp)[idx] = make_float4(cx, cy, w, h);
}

// ---------------------------------------------------------------- geo (MFMA, fp16)
// Round-7: B-fragments (loop-invariant) hoisted out of the slab loop into
// 16 f16x8 registers -- removes 48 of 64 ds_read_b128 per thread (VGPR 44->~110;
// compiler provably wasn't hoisting at 44 VGPRs).
__global__ __launch_bounds__(256) void k_geo(const float* __restrict__ boxp,
                                             const float* __restrict__ Wg,
                                             const float* __restrict__ bg,
                                             const float* __restrict__ divm,
                                             __half* __restrict__ geo) {
    __shared__ _Float16 WgT[32 * 256];   // [n][k] fp16, k XOR-swizzled by (n&7)<<3
    __shared__ __half obuf[4][24][68];   // per-wave: [t][j-within-64], pad 68
    const int tid = threadIdx.x;
    for (int idx = tid; idx < 32 * 256; idx += 256) {
        int n = idx >> 8, k = idx & 255;
        float w = (n < 24) ? Wg[(size_t)(n >> 3) * 2048 + (size_t)k * 8 + (n & 7)] : 0.f;
        WgT[n * 256 + (k ^ ((n & 7) << 3))] = (_Float16)w;
    }
    __syncthreads();

    const int lane = tid & 63;
    const int wid  = tid >> 6;
    const int ln15 = lane & 15;
    const int kgrp = lane >> 4;          // 0..3

    float invd[8];
    {
        const float4* dv4 = reinterpret_cast<const float4*>(divm);
        float4 da = dv4[kgrp * 2], db = dv4[kgrp * 2 + 1];
        invd[0] = INV2PI / da.x; invd[1] = INV2PI / da.y;
        invd[2] = INV2PI / da.z; invd[3] = INV2PI / da.w;
        invd[4] = INV2PI / db.x; invd[5] = INV2PI / db.y;
        invd[6] = INV2PI / db.z; invd[7] = INV2PI / db.w;
    }
    const int n0 = ln15;            // output col, tile 0 (always < 24)
    const int n1 = 16 + ln15;       // output col, tile 1 (valid if < 24)
    const float bg0 = bg[n0];
    const float bg1 = (n1 < 24) ? bg[n1] : 0.f;

    // swizzle involution split into disjoint bit-fields (round-4 fix)
    const int mask  = (ln15 & 7) << 3;          // bits 3..5
    const int flip5 = mask & 32;                // bit 5 -> flips kc low bit
    const int kb    = (kgrp << 3) ^ (mask & 24);
    const int base0 = n0 * 256 + kb;
    const int base1 = n1 * 256 + kb;

    // hoisted, loop-invariant B-fragments
    f16x8 bS0[4], bC0[4], bS1[4], bC1[4];
#pragma unroll
    for (int kc2 = 0; kc2 < 4; ++kc2) {
        const int koffS = ((2 * kc2) * 32) ^ flip5;
        const int koffC = ((2 * kc2 + 1) * 32) ^ flip5;
        bS0[kc2] = *reinterpret_cast<const f16x8*>(&WgT[base0 + koffS]);
        bC0[kc2] = *reinterpret_cast<const f16x8*>(&WgT[base0 + koffC]);
        bS1[kc2] = *reinterpret_cast<const f16x8*>(&WgT[base1 + koffS]);
        bC1[kc2] = *reinterpret_cast<const f16x8*>(&WgT[base1 + koffC]);
    }

    const float4* boxp4 = reinterpret_cast<const float4*>(boxp);
    const size_t plane = (size_t)NNq * NNq;

    const int base4 = (blockIdx.x * 4 + wid) * 4;   // 4 consecutive slabs per wave
#pragma unroll
    for (int it = 0; it < 4; ++it) {
        const int slab = base4 + it;
        const int p0 = slab << 4;
        const int b  = p0 >> 18;
        const int rem = p0 & (NNq * NNq - 1);
        const int i  = rem >> 9;
        const int j0 = rem & (NNq - 1);

        float4 bi = boxp4[b * NNq + i];
        float4 bj = boxp4[b * NNq + j0 + ln15];
        float rel[4];
        rel[0] = __logf(fabsf(bj.x - bi.x) / bj.z + EPSF);
        rel[1] = __logf(fabsf(bj.y - bi.y) / bj.w + EPSF);
        rel[2] = __logf(bi.z / bj.z + EPSF);
        rel[3] = __logf(bi.w / bj.w + EPSF);

        f32x4 acc0 = {0.f, 0.f, 0.f, 0.f};
        f32x4 acc1 = {0.f, 0.f, 0.f, 0.f};

#pragma unroll
        for (int kc2 = 0; kc2 < 4; ++kc2) {
            const float rc = rel[kc2];
            f16x8 afs, afc;
#pragma unroll
            for (int j = 0; j < 8; ++j) {
                float rv = FRACTF(rc * invd[j]);
                afs[j] = (_Float16)SINR(rv);
                afc[j] = (_Float16)COSR(rv);
            }
            acc0 = __builtin_amdgcn_mfma_f32_16x16x32_f16(afs, bS0[kc2], acc0, 0, 0, 0);
            acc0 = __builtin_amdgcn_mfma_f32_16x16x32_f16(afc, bC0[kc2], acc0, 0, 0, 0);
            acc1 = __builtin_amdgcn_mfma_f32_16x16x32_f16(afs, bS1[kc2], acc1, 0, 0, 0);
            acc1 = __builtin_amdgcn_mfma_f32_16x16x32_f16(afc, bC1[kc2], acc1, 0, 0, 0);
        }

#pragma unroll
        for (int r = 0; r < 4; ++r) {
            const int m = it * 16 + (kgrp << 2) + r;    // j within the 64-run
            float g0 = fmaxf(acc0[r] + bg0, 0.f);
            obuf[wid][n0][m] = __float2half(g0);
            if (n1 < 24) {
                float g1 = fmaxf(acc1[r] + bg1, 0.f);
                obuf[wid][n1][m] = __float2half(g1);
            }
        }
    }
    __syncthreads();

    // coalesced write-out: 24 rows of 64 contiguous halfs (128B each)
    const int b_  = base4 >> 14;
    const int i_  = (base4 >> 5) & (NNq - 1);
    const int j0b = (base4 & 31) << 4;
    size_t obase = (size_t)b_ * plane + (size_t)i_ * NNq + j0b + lane;
#pragma unroll
    for (int t = 0; t < 24; ++t) {
        geo[obase + (size_t)t * (BB * plane)] = obuf[wid][t][lane];
    }
}

// ---------------------------------------------------------------- GEMM (MFMA fp16)
#define LDP 264
__global__ __launch_bounds__(256) void k_gemm_mfma(const float* __restrict__ A,
        const float* __restrict__ W0, const float* __restrict__ W1, const float* __restrict__ W2,
        const float* __restrict__ b0, const float* __restrict__ b1, const float* __restrict__ b2,
        float* __restrict__ C0, float* __restrict__ C1, float* __restrict__ C2,
        const float* __restrict__ resid) {
    const float* W   = (blockIdx.z == 0) ? W0 : (blockIdx.z == 1) ? W1 : W2;
    const float* bia = (blockIdx.z == 0) ? b0 : (blockIdx.z == 1) ? b1 : b2;
    float*       C   = (blockIdx.z == 0) ? C0 : (blockIdx.z == 1) ? C1 : C2;

    __shared__ _Float16 As[64 * LDP];   // [m][k] fp16, padded
    __shared__ _Float16 Ws[64 * LDP];   // [n][k] fp16 (W transposed), padded

    const int tid = threadIdx.x;
    const int m0 = blockIdx.x * 64, n0 = blockIdx.y * 64;

    for (int u = tid; u < 64 * 64; u += 256) {          // A: float4 units
        int m = u >> 6, k4 = (u & 63) * 4;
        float4 av = *reinterpret_cast<const float4*>(&A[(size_t)(m0 + m) * 256 + k4]);
        _Float16* dst = &As[m * LDP + k4];
        dst[0] = (_Float16)av.x; dst[1] = (_Float16)av.y;
        dst[2] = (_Float16)av.z; dst[3] = (_Float16)av.w;
    }
    for (int u = tid; u < 64 * 64; u += 256) {          // W transposed
        int n = u & 63, k4 = (u >> 6) * 4;
#pragma unroll
        for (int e = 0; e < 4; ++e)
            Ws[n * LDP + k4 + e] = (_Float16)W[(size_t)(k4 + e) * 256 + n0 + n];
    }
    __syncthreads();

    const int lane = tid & 63;
    const int wid  = tid >> 6;
    const int ln15 = lane & 15;
    const int kgrp = lane >> 4;
    const int mw   = wid * 16;
    const int kfr  = kgrp * 8;

    f32x4 acc[4] = {{0.f,0.f,0.f,0.f},{0.f,0.f,0.f,0.f},
                    {0.f,0.f,0.f,0.f},{0.f,0.f,0.f,0.f}};
#pragma unroll
    for (int kc = 0; kc < 8; ++kc) {
        f16x8 af = *reinterpret_cast<const f16x8*>(&As[(mw + ln15) * LDP + kc * 32 + kfr]);
#pragma unroll
        for (int nt = 0; nt < 4; ++nt) {
            f16x8 bf = *reinterpret_cast<const f16x8*>(&Ws[(nt * 16 + ln15) * LDP + kc * 32 + kfr]);
            acc[nt] = __builtin_amdgcn_mfma_f32_16x16x32_f16(af, bf, acc[nt], 0, 0, 0);
        }
    }

#pragma unroll
    for (int nt = 0; nt < 4; ++nt) {
        const int col = n0 + nt * 16 + ln15;
        const float bv = bia[col];
#pragma unroll
        for (int r = 0; r < 4; ++r) {
            const int row = m0 + mw + kgrp * 4 + r;
            float o = fmaxf(acc[nt][r] + bv, 0.f);
            if (resid) o += resid[(size_t)row * 256 + col];
            C[(size_t)row * 256 + col] = o;
        }
    }
}

// ---------------------------------------------------------------- fused attention (MFMA)
// Block = (b,h) x 32 q-rows, 4 waves. Per 128-j block: stage Kh[j][d], VT[d][j]
// fp16; QK^T via mfma_16x16x32_f16 (wave w owns j-slice w*32: 2 m-tiles x 2
// j-tiles); two-level online softmax (per-wave partials over its 32 cols ->
// combine by tid<32 -> rescale P~ to global max); P stored fp16 to Ph; PV via
// MFMA (wave owns one 16x16 O tile, A=Ph[i][j], B=VT[d][j]), O rescaled by
// rowc each jb. Fragment recipe identical to k_gemm_mfma (verified).
__global__ __launch_bounds__(256) void k_attn(const float* __restrict__ q,
                                              const float* __restrict__ kk,
                                              const float* __restrict__ vv,
                                              const __half* __restrict__ geo,
                                              const int* __restrict__ maskp,
                                              float* __restrict__ y, int l) {
    const int bh = blockIdx.y;
    const int b = bh >> 3, h = bh & 7;
    const int i0t = blockIdx.x * 32;

    __shared__ _Float16 Qh[32][40];     // pad 40 halfs = 80B (16B-aligned rows)
    __shared__ _Float16 Kh[128][40];
    __shared__ _Float16 VT[32][136];    // [d][j], 272B rows
    __shared__ _Float16 Ph[32][136];
    __shared__ float tmax[4][32], tsum[4][32], rowsc[4][32];
    __shared__ float rowm[32], rowl[32], rowc[32];

    const int tid  = threadIdx.x;
    const int lane = tid & 63, wid = tid >> 6;
    const int ln15 = lane & 15, kgrp = lane >> 4;
    const int mt = wid >> 1, dt = wid & 1;      // PV tile ownership

    {   // stage Q fp32->fp16 (32 x 32)
        int i = tid >> 3, d4 = (tid & 7) * 4;
        float4 qv = *reinterpret_cast<const float4*>(
            &q[(size_t)(b * NNq + i0t + i) * DDm + h * DHh + d4]);
        Qh[i][d4 + 0] = (_Float16)qv.x; Qh[i][d4 + 1] = (_Float16)qv.y;
        Qh[i][d4 + 2] = (_Float16)qv.z; Qh[i][d4 + 3] = (_Float16)qv.w;
    }
    if (tid < 32) { rowm[tid] = -3.0e38f; rowl[tid] = 0.f; }

    f32x4 oacc = {0.f, 0.f, 0.f, 0.f};
    const size_t plane = (size_t)NNq * NNq;
    const size_t geo_base = (size_t)((l * 8 + h) * BB + b) * plane;

    for (int jb = 0; jb < 4; ++jb) {
        const int j0t = jb * 128;
        __syncthreads();
        // stage Kh [128][32] and VT [32][128] (fp32 -> fp16)
#pragma unroll
        for (int r = 0; r < 4; ++r) {
            int u = r * 256 + tid;          // 1024 float4 units
            int j = u >> 3, d4 = (u & 7) * 4;
            float4 kv = *reinterpret_cast<const float4*>(
                &kk[(size_t)(b * NNq + j0t + j) * DDm + h * DHh + d4]);
            Kh[j][d4 + 0] = (_Float16)kv.x; Kh[j][d4 + 1] = (_Float16)kv.y;
            Kh[j][d4 + 2] = (_Float16)kv.z; Kh[j][d4 + 3] = (_Float16)kv.w;
            float4 vv4 = *reinterpret_cast<const float4*>(
                &vv[(size_t)(b * NNq + j0t + j) * DDm + h * DHh + d4]);
            VT[d4 + 0][j] = (_Float16)vv4.x; VT[d4 + 1][j] = (_Float16)vv4.y;
            VT[d4 + 2][j] = (_Float16)vv4.z; VT[d4 + 3][j] = (_Float16)vv4.w;
        }
        __syncthreads();

        // QK^T: wave's j-slice = wid*32 .. +32
        f32x4 sacc[2][2];
#pragma unroll
        for (int a = 0; a < 2; ++a)
#pragma unroll
            for (int c = 0; c < 2; ++c) sacc[a][c] = (f32x4){0.f, 0.f, 0.f, 0.f};
#pragma unroll
        for (int mt2 = 0; mt2 < 2; ++mt2) {
            f16x8 af = *reinterpret_cast<const f16x8*>(&Qh[mt2 * 16 + ln15][kgrp * 8]);
#pragma unroll
            for (int jt = 0; jt < 2; ++jt) {
                f16x8 bf = *reinterpret_cast<const f16x8*>(
                    &Kh[wid * 32 + jt * 16 + ln15][kgrp * 8]);
                sacc[mt2][jt] = __builtin_amdgcn_mfma_f32_16x16x32_f16(af, bf, sacc[mt2][jt], 0, 0, 0);
            }
        }

        // epilogue: geo/mask, per-wave row stats over its 32 cols
        float pv[2][2][4];
#pragma unroll
        for (int mt2 = 0; mt2 < 2; ++mt2) {
#pragma unroll
            for (int r = 0; r < 4; ++r) {
                const int row = mt2 * 16 + kgrp * 4 + r;
                const int ig = i0t + row;
                const int jg0 = j0t + wid * 32 + ln15;
                const int jg1 = jg0 + 16;
                float g0 = __half2float(geo[geo_base + (size_t)ig * NNq + jg0]);
                float g1 = __half2float(geo[geo_base + (size_t)ig * NNq + jg1]);
                float s0 = sacc[mt2][0][r] * SCALE + __logf(g0 + 1e-6f);
                float s1 = sacc[mt2][1][r] * SCALE + __logf(g1 + 1e-6f);
                if (maskp[(size_t)(b * NNq + ig) * NNq + jg0] == 0) s0 = -1e9f;
                if (maskp[(size_t)(b * NNq + ig) * NNq + jg1] == 0) s1 = -1e9f;
                float pm = fmaxf(s0, s1);
#pragma unroll
                for (int o = 8; o > 0; o >>= 1) pm = fmaxf(pm, __shfl_xor(pm, o, 64));
                float e0 = __expf(s0 - pm), e1 = __expf(s1 - pm);
                float ps = e0 + e1;
#pragma unroll
                for (int o = 8; o > 0; o >>= 1) ps += __shfl_xor(ps, o, 64);
                pv[mt2][0][r] = e0; pv[mt2][1][r] = e1;
                if (ln15 == 0) { tmax[wid][row] = pm; tsum[wid][row] = ps; }
            }
        }
        __syncthreads();

        if (tid < 32) {   // combine 4 wave-partials into running (m,l), per row
            float m0 = tmax[0][tid], m1 = tmax[1][tid], m2 = tmax[2][tid], m3 = tmax[3][tid];
            float M  = fmaxf(fmaxf(m0, m1), fmaxf(m2, m3));
            float mold = rowm[tid];
            float mnew = fmaxf(mold, M);
            float c  = __expf(mold - mnew);
            float w0 = __expf(m0 - mnew), w1 = __expf(m1 - mnew);
            float w2 = __expf(m2 - mnew), w3 = __expf(m3 - mnew);
            rowsc[0][tid] = w0; rowsc[1][tid] = w1; rowsc[2][tid] = w2; rowsc[3][tid] = w3;
            rowl[tid] = rowl[tid] * c + tsum[0][tid] * w0 + tsum[1][tid] * w1
                                      + tsum[2][tid] * w2 + tsum[3][tid] * w3;
            rowm[tid] = mnew;
            rowc[tid] = c;
        }
        __syncthreads();

        // rescale P~ to global max, store fp16
#pragma unroll
        for (int mt2 = 0; mt2 < 2; ++mt2) {
#pragma unroll
            for (int r = 0; r < 4; ++r) {
                const int row = mt2 * 16 + kgrp * 4 + r;
                float sc = rowsc[wid][row];
                Ph[row][wid * 32 + ln15]      = (_Float16)(pv[mt2][0][r] * sc);
                Ph[row][wid * 32 + 16 + ln15] = (_Float16)(pv[mt2][1][r] * sc);
            }
        }
        __syncthreads();

        // PV: wave owns O tile (mt, dt); rescale then accumulate this jb
        {
            const int rowbase = mt * 16 + kgrp * 4;
            oacc[0] *= rowc[rowbase + 0];
            oacc[1] *= rowc[rowbase + 1];
            oacc[2] *= rowc[rowbase + 2];
            oacc[3] *= rowc[rowbase + 3];
#pragma unroll
            for (int kc = 0; kc < 4; ++kc) {
                f16x8 pa = *reinterpret_cast<const f16x8*>(&Ph[mt * 16 + ln15][kc * 32 + kgrp * 8]);
                f16x8 vb = *reinterpret_cast<const f16x8*>(&VT[dt * 16 + ln15][kc * 32 + kgrp * 8]);
                oacc = __builtin_amdgcn_mfma_f32_16x16x32_f16(pa, vb, oacc, 0, 0, 0);
            }
        }
    }

    // final normalize + write (rowl final after last combine, barrier-covered)
    const int rowbase = mt * 16 + kgrp * 4;
#pragma unroll
    for (int r = 0; r < 4; ++r) {
        float inv = 1.0f / rowl[rowbase + r];
        y[(size_t)(b * NNq + i0t + rowbase + r) * DDm + h * DHh + dt * 16 + ln15] = oacc[r] * inv;
    }
}

// ---------------------------------------------------------------- launch
extern "C" void kernel_launch(void* const* d_in, const int* in_sizes, int n_in,
                              void* d_out, int out_size, void* d_ws, size_t ws_size,
                              hipStream_t stream) {
    const float* boxes    = (const float*)d_in[0];
    const float* features = (const float*)d_in[1];
    const int*   mask     = (const int*)d_in[2];
    const float* Wq = (const float*)d_in[3];
    const float* bq = (const float*)d_in[4];
    const float* Wk = (const float*)d_in[5];
    const float* bk = (const float*)d_in[6];
    const float* Wv = (const float*)d_in[7];
    const float* bv = (const float*)d_in[8];
    const float* Wo = (const float*)d_in[9];
    const float* bo = (const float*)d_in[10];
    const float* Wg = (const float*)d_in[11];
    const float* bg = (const float*)d_in[12];
    const float* dv = (const float*)d_in[13];

    char* ws = (char*)d_ws;
    float*  boxp = (float*)(ws);                              //    16,384
    __half* geo  = (__half*)(ws + 16384);                     // 25,165,824
    float*  qb   = (float*)(ws + 25182208);                   //  1,048,576
    float*  kb   = (float*)(ws + 26230784);                   //  1,048,576
    float*  vb   = (float*)(ws + 27279360);                   //  1,048,576
    float*  yb   = (float*)(ws + 28327936);                   //  1,048,576  -> ~29.4 MB
    float*  x    = (float*)d_out;

    k_boxprep<<<dim3((BB * NNq + 255) / 256), dim3(256), 0, stream>>>(boxes, boxp);
    k_geo<<<dim3(2048), dim3(256), 0, stream>>>(boxp, Wg, bg, dv, geo);

    for (int l = 0; l < LLn; ++l) {
        const float* Wq_l = Wq + (size_t)l * DDm * DDm;
        const float* Wk_l = Wk + (size_t)l * DDm * DDm;
        const float* Wv_l = Wv + (size_t)l * DDm * DDm;
        const float* Wo_l = Wo + (size_t)l * DDm * DDm;
        const float* bq_l = bq + (size_t)l * DDm;
        const float* bk_l = bk + (size_t)l * DDm;
        const float* bv_l = bv + (size_t)l * DDm;
        const float* bo_l = bo + (size_t)l * DDm;
        const float* xin  = (l == 0) ? features : x;   // layer-0 reads features directly

        k_gemm_mfma<<<dim3(16, 4, 3), dim3(256), 0, stream>>>(
            xin, Wq_l, Wk_l, Wv_l, bq_l, bk_l, bv_l, qb, kb, vb, nullptr);
        k_attn<<<dim3(16, 16), dim3(256), 0, stream>>>(qb, kb, vb, geo, mask, yb, l);
        k_gemm_mfma<<<dim3(16, 4, 1), dim3(256), 0, stream>>>(
            yb, Wo_l, Wo_l, Wo_l, bo_l, bo_l, bo_l, x, x, x, xin);
    }
}

// Round 8
// 227.736 us; speedup vs baseline: 1.1136x; 1.1136x over previous
//
#include <hip/hip_runtime.h>
#include <hip/hip_fp16.h>

// Problem constants (from reference): B=2, N=512, D=256, H=8, L=3
#define BB 2
#define NNq 512
#define DDm 256
#define HHh 8
#define DHh 32
#define LLn 3

static constexpr float EPSF   = 1e-4f;
static constexpr float INV2PI = 0.15915494309189535f;   // 1/(2*pi)
static constexpr float SCALE  = 0.17677669529663687f;   // 1/sqrt(32)

#if __has_builtin(__builtin_amdgcn_fractf)
#define FRACTF(x) __builtin_amdgcn_fractf(x)
#else
#define FRACTF(x) ((x) - floorf(x))
#endif
#if __has_builtin(__builtin_amdgcn_sinf)
#define SINR(x) __builtin_amdgcn_sinf(x)   // sin(2*pi*x), x in revolutions
#define COSR(x) __builtin_amdgcn_cosf(x)
#else
#define SINR(x) __sinf((x) * 6.2831853071795865f)
#define COSR(x) __cosf((x) * 6.2831853071795865f)
#endif

struct __align__(8) H4 { __half a, b, c, d; };

typedef _Float16 f16x8 __attribute__((ext_vector_type(8)));
typedef _Float16 f16x4 __attribute__((ext_vector_type(4)));
typedef float    f32x4 __attribute__((ext_vector_type(4)));

// ---------------------------------------------------------------- boxprep
__global__ __launch_bounds__(256) void k_boxprep(const float* __restrict__ boxes,
                                                 float* __restrict__ boxp) {
    int idx = blockIdx.x * 256 + threadIdx.x;
    if (idx >= BB * NNq) return;
    float4 bx = reinterpret_cast<const float4*>(boxes)[idx];
    float cx = 0.5f * (bx.x + bx.z), cy = 0.5f * (bx.y + bx.w);
    float w = fmaxf(bx.z - bx.x, EPSF), h = fmaxf(bx.w - bx.y, EPSF);
    reinterpret_cast<float4*>(boxp)[idx] = make_float4(cx, cy, w, h);
}

// ---------------------------------------------------------------- geo (MFMA, fp16)
// Round-8: write-out now stores LG = mask ? log(relu(emb@Wg+bg)+1e-6) : -6e4
// as fp16 -- folds attention's per-element logf + mask application into this
// kernel (24 v_log_f32/thread here vs 64 logf + 32 loads/thread in each of the
// 3 attn dispatches). B-fragments stay hoisted (round-7, bank conflicts halved).
__global__ __launch_bounds__(256) void k_geo(const float* __restrict__ boxp,
                                             const float* __restrict__ Wg,
                                             const float* __restrict__ bg,
                                             const float* __restrict__ divm,
                                             const int* __restrict__ maskp,
                                             __half* __restrict__ lg) {
    __shared__ _Float16 WgT[32 * 256];   // [n][k] fp16, k XOR-swizzled by (n&7)<<3
    __shared__ __half obuf[4][24][68];   // per-wave: [t][j-within-64], pad 68
    const int tid = threadIdx.x;
    for (int idx = tid; idx < 32 * 256; idx += 256) {
        int n = idx >> 8, k = idx & 255;
        float w = (n < 24) ? Wg[(size_t)(n >> 3) * 2048 + (size_t)k * 8 + (n & 7)] : 0.f;
        WgT[n * 256 + (k ^ ((n & 7) << 3))] = (_Float16)w;
    }
    __syncthreads();

    const int lane = tid & 63;
    const int wid  = tid >> 6;
    const int ln15 = lane & 15;
    const int kgrp = lane >> 4;          // 0..3

    float invd[8];
    {
        const float4* dv4 = reinterpret_cast<const float4*>(divm);
        float4 da = dv4[kgrp * 2], db = dv4[kgrp * 2 + 1];
        invd[0] = INV2PI / da.x; invd[1] = INV2PI / da.y;
        invd[2] = INV2PI / da.z; invd[3] = INV2PI / da.w;
        invd[4] = INV2PI / db.x; invd[5] = INV2PI / db.y;
        invd[6] = INV2PI / db.z; invd[7] = INV2PI / db.w;
    }
    const int n0 = ln15;            // output col, tile 0 (always < 24)
    const int n1 = 16 + ln15;       // output col, tile 1 (valid if < 24)
    const float bg0 = bg[n0];
    const float bg1 = (n1 < 24) ? bg[n1] : 0.f;

    // swizzle involution split into disjoint bit-fields (round-4 fix)
    const int mask  = (ln15 & 7) << 3;          // bits 3..5
    const int flip5 = mask & 32;                // bit 5 -> flips kc low bit
    const int kb    = (kgrp << 3) ^ (mask & 24);
    const int base0 = n0 * 256 + kb;
    const int base1 = n1 * 256 + kb;

    // hoisted, loop-invariant B-fragments
    f16x8 bS0[4], bC0[4], bS1[4], bC1[4];
#pragma unroll
    for (int kc2 = 0; kc2 < 4; ++kc2) {
        const int koffS = ((2 * kc2) * 32) ^ flip5;
        const int koffC = ((2 * kc2 + 1) * 32) ^ flip5;
        bS0[kc2] = *reinterpret_cast<const f16x8*>(&WgT[base0 + koffS]);
        bC0[kc2] = *reinterpret_cast<const f16x8*>(&WgT[base0 + koffC]);
        bS1[kc2] = *reinterpret_cast<const f16x8*>(&WgT[base1 + koffS]);
        bC1[kc2] = *reinterpret_cast<const f16x8*>(&WgT[base1 + koffC]);
    }

    const float4* boxp4 = reinterpret_cast<const float4*>(boxp);
    const size_t plane = (size_t)NNq * NNq;

    const int base4 = (blockIdx.x * 4 + wid) * 4;   // 4 consecutive slabs per wave
#pragma unroll
    for (int it = 0; it < 4; ++it) {
        const int slab = base4 + it;
        const int p0 = slab << 4;
        const int b  = p0 >> 18;
        const int rem = p0 & (NNq * NNq - 1);
        const int i  = rem >> 9;
        const int j0 = rem & (NNq - 1);

        float4 bi = boxp4[b * NNq + i];
        float4 bj = boxp4[b * NNq + j0 + ln15];
        float rel[4];
        rel[0] = __logf(fabsf(bj.x - bi.x) / bj.z + EPSF);
        rel[1] = __logf(fabsf(bj.y - bi.y) / bj.w + EPSF);
        rel[2] = __logf(bi.z / bj.z + EPSF);
        rel[3] = __logf(bi.w / bj.w + EPSF);

        f32x4 acc0 = {0.f, 0.f, 0.f, 0.f};
        f32x4 acc1 = {0.f, 0.f, 0.f, 0.f};

#pragma unroll
        for (int kc2 = 0; kc2 < 4; ++kc2) {
            const float rc = rel[kc2];
            f16x8 afs, afc;
#pragma unroll
            for (int j = 0; j < 8; ++j) {
                float rv = FRACTF(rc * invd[j]);
                afs[j] = (_Float16)SINR(rv);
                afc[j] = (_Float16)COSR(rv);
            }
            acc0 = __builtin_amdgcn_mfma_f32_16x16x32_f16(afs, bS0[kc2], acc0, 0, 0, 0);
            acc0 = __builtin_amdgcn_mfma_f32_16x16x32_f16(afc, bC0[kc2], acc0, 0, 0, 0);
            acc1 = __builtin_amdgcn_mfma_f32_16x16x32_f16(afs, bS1[kc2], acc1, 0, 0, 0);
            acc1 = __builtin_amdgcn_mfma_f32_16x16x32_f16(afc, bC1[kc2], acc1, 0, 0, 0);
        }

#pragma unroll
        for (int r = 0; r < 4; ++r) {
            const int m = it * 16 + (kgrp << 2) + r;    // j within the 64-run
            float g0 = fmaxf(acc0[r] + bg0, 0.f);
            obuf[wid][n0][m] = __float2half(g0);
            if (n1 < 24) {
                float g1 = fmaxf(acc1[r] + bg1, 0.f);
                obuf[wid][n1][m] = __float2half(g1);
            }
        }
    }
    __syncthreads();

    // coalesced write-out with log+mask fold: 24 rows of 64 contiguous halfs
    const int b_  = base4 >> 14;
    const int i_  = (base4 >> 5) & (NNq - 1);
    const int j0b = (base4 & 31) << 4;
    const int mv  = maskp[((size_t)b_ * NNq + i_) * NNq + j0b + lane];
    size_t obase = (size_t)b_ * plane + (size_t)i_ * NNq + j0b + lane;
#pragma unroll
    for (int t = 0; t < 24; ++t) {
        float g = __half2float(obuf[wid][t][lane]);
        float v = (mv != 0) ? __logf(g + 1e-6f) : -60000.0f;
        lg[obase + (size_t)t * (BB * plane)] = __float2half(v);
    }
}

// ---------------------------------------------------------------- GEMM (MFMA fp16)
#define LDP 264
__global__ __launch_bounds__(256) void k_gemm_mfma(const float* __restrict__ A,
        const float* __restrict__ W0, const float* __restrict__ W1, const float* __restrict__ W2,
        const float* __restrict__ b0, const float* __restrict__ b1, const float* __restrict__ b2,
        float* __restrict__ C0, float* __restrict__ C1, float* __restrict__ C2,
        const float* __restrict__ resid) {
    const float* W   = (blockIdx.z == 0) ? W0 : (blockIdx.z == 1) ? W1 : W2;
    const float* bia = (blockIdx.z == 0) ? b0 : (blockIdx.z == 1) ? b1 : b2;
    float*       C   = (blockIdx.z == 0) ? C0 : (blockIdx.z == 1) ? C1 : C2;

    __shared__ _Float16 As[64 * LDP];   // [m][k] fp16, padded
    __shared__ _Float16 Ws[64 * LDP];   // [n][k] fp16 (W transposed), padded

    const int tid = threadIdx.x;
    const int m0 = blockIdx.x * 64, n0 = blockIdx.y * 64;

    for (int u = tid; u < 64 * 64; u += 256) {          // A: float4 units
        int m = u >> 6, k4 = (u & 63) * 4;
        float4 av = *reinterpret_cast<const float4*>(&A[(size_t)(m0 + m) * 256 + k4]);
        f16x4 hv = {(_Float16)av.x, (_Float16)av.y, (_Float16)av.z, (_Float16)av.w};
        *reinterpret_cast<f16x4*>(&As[m * LDP + k4]) = hv;
    }
    for (int u = tid; u < 64 * 64; u += 256) {          // W transposed
        int n = u & 63, k4 = (u >> 6) * 4;
        f16x4 hv = {(_Float16)W[(size_t)(k4 + 0) * 256 + n0 + n],
                    (_Float16)W[(size_t)(k4 + 1) * 256 + n0 + n],
                    (_Float16)W[(size_t)(k4 + 2) * 256 + n0 + n],
                    (_Float16)W[(size_t)(k4 + 3) * 256 + n0 + n]};
        *reinterpret_cast<f16x4*>(&Ws[n * LDP + k4]) = hv;
    }
    __syncthreads();

    const int lane = tid & 63;
    const int wid  = tid >> 6;
    const int ln15 = lane & 15;
    const int kgrp = lane >> 4;
    const int mw   = wid * 16;
    const int kfr  = kgrp * 8;

    f32x4 acc[4] = {{0.f,0.f,0.f,0.f},{0.f,0.f,0.f,0.f},
                    {0.f,0.f,0.f,0.f},{0.f,0.f,0.f,0.f}};
#pragma unroll
    for (int kc = 0; kc < 8; ++kc) {
        f16x8 af = *reinterpret_cast<const f16x8*>(&As[(mw + ln15) * LDP + kc * 32 + kfr]);
#pragma unroll
        for (int nt = 0; nt < 4; ++nt) {
            f16x8 bf = *reinterpret_cast<const f16x8*>(&Ws[(nt * 16 + ln15) * LDP + kc * 32 + kfr]);
            acc[nt] = __builtin_amdgcn_mfma_f32_16x16x32_f16(af, bf, acc[nt], 0, 0, 0);
        }
    }

#pragma unroll
    for (int nt = 0; nt < 4; ++nt) {
        const int col = n0 + nt * 16 + ln15;
        const float bv = bia[col];
#pragma unroll
        for (int r = 0; r < 4; ++r) {
            const int row = m0 + mw + kgrp * 4 + r;
            float o = fmaxf(acc[nt][r] + bv, 0.f);
            if (resid) o += resid[(size_t)row * 256 + col];
            C[(size_t)row * 256 + col] = o;
        }
    }
}

// ---------------------------------------------------------------- fused attention
// Round-6 proven VALU structure; round-8 epilogue reads precomputed LG fp16
// (log+mask already folded in k_geo) -- no logf, no mask loads here.
__global__ __launch_bounds__(256) void k_attn(const float* __restrict__ q,
                                              const float* __restrict__ kk,
                                              const float* __restrict__ vv,
                                              const __half* __restrict__ lg,
                                              float* __restrict__ y, int l) {
    const int bh = blockIdx.y;
    const int b = bh >> 3, h = bh & 7;
    const int i0t = blockIdx.x * 32;

    __shared__ float Qs[32][36];
    __shared__ float Kst[32][132];   // [d][j] transposed
    __shared__ float Vs[128][36];
    __shared__ float Ps[32][132];
    __shared__ float rowc[32], rowl[32];

    const int tid = threadIdx.x;
    const int tx = tid & 31, ty = tid >> 5;
    const int si0 = ty * 4, sj0 = tx * 4;
    const int prow = tid >> 3, pd4 = (tid & 7) * 4;

    {   // load Q tile
        int i = tid >> 3, d4 = (tid & 7) * 4;
        *reinterpret_cast<float4*>(&Qs[i][d4]) = *reinterpret_cast<const float4*>(
            &q[(size_t)(b * NNq + i0t + i) * DDm + h * DHh + d4]);
    }

    float m_r[4], l_r[4];
#pragma unroll
    for (int e = 0; e < 4; ++e) { m_r[e] = -3.0e38f; l_r[e] = 0.f; }
    float4 oacc = make_float4(0.f, 0.f, 0.f, 0.f);

    const size_t plane = (size_t)NNq * NNq;
    const size_t lg_base = (size_t)((l * 8 + h) * BB + b) * plane;

    for (int jb = 0; jb < 4; ++jb) {
        const int j0t = jb * 128;
        __syncthreads();
#pragma unroll
        for (int r = 0; r < 4; ++r) {   // K transposed
            int idx = r * 256 + tid;
            int j = idx >> 3, d4 = (idx & 7) * 4;
            float4 kv = *reinterpret_cast<const float4*>(
                &kk[(size_t)(b * NNq + j0t + j) * DDm + h * DHh + d4]);
            Kst[d4 + 0][j] = kv.x; Kst[d4 + 1][j] = kv.y;
            Kst[d4 + 2][j] = kv.z; Kst[d4 + 3][j] = kv.w;
        }
#pragma unroll
        for (int r = 0; r < 4; ++r) {   // V
            int idx = r * 256 + tid;
            int j = idx >> 3, d4 = (idx & 7) * 4;
            *reinterpret_cast<float4*>(&Vs[j][d4]) = *reinterpret_cast<const float4*>(
                &vv[(size_t)(b * NNq + j0t + j) * DDm + h * DHh + d4]);
        }
        __syncthreads();

        float acc[4][4] = {};
#pragma unroll 8
        for (int d = 0; d < 32; ++d) {
            float4 kv = *reinterpret_cast<const float4*>(&Kst[d][sj0]);
#pragma unroll
            for (int e = 0; e < 4; ++e) {
                float a = Qs[si0 + e][d];
                acc[e][0] = fmaf(a, kv.x, acc[e][0]);
                acc[e][1] = fmaf(a, kv.y, acc[e][1]);
                acc[e][2] = fmaf(a, kv.z, acc[e][2]);
                acc[e][3] = fmaf(a, kv.w, acc[e][3]);
            }
        }

#pragma unroll
        for (int e = 0; e < 4; ++e) {
            int ig = i0t + si0 + e;
            int jg = j0t + sj0;
            H4 g4 = *reinterpret_cast<const H4*>(&lg[lg_base + (size_t)ig * NNq + jg]);
            float4 sv;
            sv.x = acc[e][0] * SCALE + __half2float(g4.a);
            sv.y = acc[e][1] * SCALE + __half2float(g4.b);
            sv.z = acc[e][2] * SCALE + __half2float(g4.c);
            sv.w = acc[e][3] * SCALE + __half2float(g4.d);

            float mx = fmaxf(fmaxf(sv.x, sv.y), fmaxf(sv.z, sv.w));
#pragma unroll
            for (int o = 16; o > 0; o >>= 1) mx = fmaxf(mx, __shfl_xor(mx, o, 32));
            float mnew = fmaxf(m_r[e], mx);
            float c = __expf(m_r[e] - mnew);
            sv.x = __expf(sv.x - mnew); sv.y = __expf(sv.y - mnew);
            sv.z = __expf(sv.z - mnew); sv.w = __expf(sv.w - mnew);
            float s4 = sv.x + sv.y + sv.z + sv.w;
#pragma unroll
            for (int o = 16; o > 0; o >>= 1) s4 += __shfl_xor(s4, o, 32);
            l_r[e] = l_r[e] * c + s4;
            m_r[e] = mnew;
            *reinterpret_cast<float4*>(&Ps[si0 + e][sj0]) = sv;
            if (tx == 0) rowc[si0 + e] = c;
        }
        __syncthreads();

        float cr = rowc[prow];
        oacc.x *= cr; oacc.y *= cr; oacc.z *= cr; oacc.w *= cr;
#pragma unroll 8
        for (int j = 0; j < 128; j += 4) {
            float4 p4 = *reinterpret_cast<const float4*>(&Ps[prow][j]);
            float4 v0 = *reinterpret_cast<const float4*>(&Vs[j + 0][pd4]);
            float4 v1 = *reinterpret_cast<const float4*>(&Vs[j + 1][pd4]);
            float4 v2 = *reinterpret_cast<const float4*>(&Vs[j + 2][pd4]);
            float4 v3 = *reinterpret_cast<const float4*>(&Vs[j + 3][pd4]);
            oacc.x = fmaf(p4.x, v0.x, oacc.x); oacc.y = fmaf(p4.x, v0.y, oacc.y);
            oacc.z = fmaf(p4.x, v0.z, oacc.z); oacc.w = fmaf(p4.x, v0.w, oacc.w);
            oacc.x = fmaf(p4.y, v1.x, oacc.x); oacc.y = fmaf(p4.y, v1.y, oacc.y);
            oacc.z = fmaf(p4.y, v1.z, oacc.z); oacc.w = fmaf(p4.y, v1.w, oacc.w);
            oacc.x = fmaf(p4.z, v2.x, oacc.x); oacc.y = fmaf(p4.z, v2.y, oacc.y);
            oacc.z = fmaf(p4.z, v2.z, oacc.z); oacc.w = fmaf(p4.z, v2.w, oacc.w);
            oacc.x = fmaf(p4.w, v3.x, oacc.x); oacc.y = fmaf(p4.w, v3.y, oacc.y);
            oacc.z = fmaf(p4.w, v3.z, oacc.z); oacc.w = fmaf(p4.w, v3.w, oacc.w);
        }
    }

    if (tx == 0) {
#pragma unroll
        for (int e = 0; e < 4; ++e) rowl[si0 + e] = l_r[e];
    }
    __syncthreads();
    float inv = 1.0f / rowl[prow];
    oacc.x *= inv; oacc.y *= inv; oacc.z *= inv; oacc.w *= inv;
    *reinterpret_cast<float4*>(&y[(size_t)(b * NNq + i0t + prow) * DDm + h * DHh + pd4]) = oacc;
}

// ---------------------------------------------------------------- launch
extern "C" void kernel_launch(void* const* d_in, const int* in_sizes, int n_in,
                              void* d_out, int out_size, void* d_ws, size_t ws_size,
                              hipStream_t stream) {
    const float* boxes    = (const float*)d_in[0];
    const float* features = (const float*)d_in[1];
    const int*   mask     = (const int*)d_in[2];
    const float* Wq = (const float*)d_in[3];
    const float* bq = (const float*)d_in[4];
    const float* Wk = (const float*)d_in[5];
    const float* bk = (const float*)d_in[6];
    const float* Wv = (const float*)d_in[7];
    const float* bv = (const float*)d_in[8];
    const float* Wo = (const float*)d_in[9];
    const float* bo = (const float*)d_in[10];
    const float* Wg = (const float*)d_in[11];
    const float* bg = (const float*)d_in[12];
    const float* dv = (const float*)d_in[13];

    char* ws = (char*)d_ws;
    float*  boxp = (float*)(ws);                              //    16,384
    __half* lg   = (__half*)(ws + 16384);                     // 25,165,824
    float*  qb   = (float*)(ws + 25182208);                   //  1,048,576
    float*  kb   = (float*)(ws + 26230784);                   //  1,048,576
    float*  vb   = (float*)(ws + 27279360);                   //  1,048,576
    float*  yb   = (float*)(ws + 28327936);                   //  1,048,576  -> ~29.4 MB
    float*  x    = (float*)d_out;

    k_boxprep<<<dim3((BB * NNq + 255) / 256), dim3(256), 0, stream>>>(boxes, boxp);
    k_geo<<<dim3(2048), dim3(256), 0, stream>>>(boxp, Wg, bg, dv, mask, lg);

    for (int l = 0; l < LLn; ++l) {
        const float* Wq_l = Wq + (size_t)l * DDm * DDm;
        const float* Wk_l = Wk + (size_t)l * DDm * DDm;
        const float* Wv_l = Wv + (size_t)l * DDm * DDm;
        const float* Wo_l = Wo + (size_t)l * DDm * DDm;
        const float* bq_l = bq + (size_t)l * DDm;
        const float* bk_l = bk + (size_t)l * DDm;
        const float* bv_l = bv + (size_t)l * DDm;
        const float* bo_l = bo + (size_t)l * DDm;
        const float* xin  = (l == 0) ? features : x;   // layer-0 reads features directly

        k_gemm_mfma<<<dim3(16, 4, 3), dim3(256), 0, stream>>>(
            xin, Wq_l, Wk_l, Wv_l, bq_l, bk_l, bv_l, qb, kb, vb, nullptr);
        k_attn<<<dim3(16, 16), dim3(256), 0, stream>>>(qb, kb, vb, lg, yb, l);
        k_gemm_mfma<<<dim3(16, 4, 1), dim3(256), 0, stream>>>(
            yb, Wo_l, Wo_l, Wo_l, bo_l, bo_l, bo_l, x, x, x, xin);
    }
}

// Round 9
// 198.643 us; speedup vs baseline: 1.2767x; 1.1465x over previous
//
#include <hip/hip_runtime.h>
#include <hip/hip_fp16.h>

// Problem constants (from reference): B=2, N=512, D=256, H=8, L=3
#define BB 2
#define NNq 512
#define DDm 256
#define HHh 8
#define DHh 32
#define LLn 3

static constexpr float EPSF   = 1e-4f;
static constexpr float INV2PI = 0.15915494309189535f;   // 1/(2*pi)
static constexpr float SCALE  = 0.17677669529663687f;   // 1/sqrt(32)

#if __has_builtin(__builtin_amdgcn_fractf)
#define FRACTF(x) __builtin_amdgcn_fractf(x)
#else
#define FRACTF(x) ((x) - floorf(x))
#endif
#if __has_builtin(__builtin_amdgcn_sinf)
#define SINR(x) __builtin_amdgcn_sinf(x)   // sin(2*pi*x), x in revolutions
#define COSR(x) __builtin_amdgcn_cosf(x)
#else
#define SINR(x) __sinf((x) * 6.2831853071795865f)
#define COSR(x) __cosf((x) * 6.2831853071795865f)
#endif

struct __align__(8) H4 { __half a, b, c, d; };

typedef _Float16 f16x8 __attribute__((ext_vector_type(8)));
typedef _Float16 f16x4 __attribute__((ext_vector_type(4)));
typedef float    f32x4 __attribute__((ext_vector_type(4)));

// ---------------------------------------------------------------- boxprep
__global__ __launch_bounds__(256) void k_boxprep(const float* __restrict__ boxes,
                                                 float* __restrict__ boxp) {
    int idx = blockIdx.x * 256 + threadIdx.x;
    if (idx >= BB * NNq) return;
    float4 bx = reinterpret_cast<const float4*>(boxes)[idx];
    float cx = 0.5f * (bx.x + bx.z), cy = 0.5f * (bx.y + bx.w);
    float w = fmaxf(bx.z - bx.x, EPSF), h = fmaxf(bx.w - bx.y, EPSF);
    reinterpret_cast<float4*>(boxp)[idx] = make_float4(cx, cy, w, h);
}

// ---------------------------------------------------------------- geo (MFMA, fp16)
// Round-9: WgT and obuf UNION the same LDS (WgT is dead after the register
// hoist of B-fragments; one barrier separates the phases). LDS 29.7KB -> 16.4KB
// => blocks/CU cap 5 -> ~8, attacking the 34% occupancy that limits this
// latency-bound kernel. Math unchanged (absmax must stay 0.03125).
__global__ __launch_bounds__(256) void k_geo(const float* __restrict__ boxp,
                                             const float* __restrict__ Wg,
                                             const float* __restrict__ bg,
                                             const float* __restrict__ divm,
                                             const int* __restrict__ maskp,
                                             __half* __restrict__ lg) {
    __shared__ char smem[16384];     // union: WgT (16384B) then obuf (13056B)
    _Float16* WgT = reinterpret_cast<_Float16*>(smem);          // [32][256]
    __half (*obuf)[24][68] = reinterpret_cast<__half (*)[24][68]>(smem);

    const int tid = threadIdx.x;
    for (int idx = tid; idx < 32 * 256; idx += 256) {
        int n = idx >> 8, k = idx & 255;
        float w = (n < 24) ? Wg[(size_t)(n >> 3) * 2048 + (size_t)k * 8 + (n & 7)] : 0.f;
        WgT[n * 256 + (k ^ ((n & 7) << 3))] = (_Float16)w;
    }
    __syncthreads();

    const int lane = tid & 63;
    const int wid  = tid >> 6;
    const int ln15 = lane & 15;
    const int kgrp = lane >> 4;          // 0..3

    float invd[8];
    {
        const float4* dv4 = reinterpret_cast<const float4*>(divm);
        float4 da = dv4[kgrp * 2], db = dv4[kgrp * 2 + 1];
        invd[0] = INV2PI / da.x; invd[1] = INV2PI / da.y;
        invd[2] = INV2PI / da.z; invd[3] = INV2PI / da.w;
        invd[4] = INV2PI / db.x; invd[5] = INV2PI / db.y;
        invd[6] = INV2PI / db.z; invd[7] = INV2PI / db.w;
    }
    const int n0 = ln15;            // output col, tile 0 (always < 24)
    const int n1 = 16 + ln15;       // output col, tile 1 (valid if < 24)
    const float bg0 = bg[n0];
    const float bg1 = (n1 < 24) ? bg[n1] : 0.f;

    // swizzle involution split into disjoint bit-fields (round-4 fix)
    const int mask  = (ln15 & 7) << 3;          // bits 3..5
    const int flip5 = mask & 32;                // bit 5 -> flips kc low bit
    const int kb    = (kgrp << 3) ^ (mask & 24);
    const int base0 = n0 * 256 + kb;
    const int base1 = n1 * 256 + kb;

    // hoist loop-invariant B-fragments into registers (WgT dead afterwards)
    f16x8 bS0[4], bC0[4], bS1[4], bC1[4];
#pragma unroll
    for (int kc2 = 0; kc2 < 4; ++kc2) {
        const int koffS = ((2 * kc2) * 32) ^ flip5;
        const int koffC = ((2 * kc2 + 1) * 32) ^ flip5;
        bS0[kc2] = *reinterpret_cast<const f16x8*>(&WgT[base0 + koffS]);
        bC0[kc2] = *reinterpret_cast<const f16x8*>(&WgT[base0 + koffC]);
        bS1[kc2] = *reinterpret_cast<const f16x8*>(&WgT[base1 + koffS]);
        bC1[kc2] = *reinterpret_cast<const f16x8*>(&WgT[base1 + koffC]);
    }
    __syncthreads();   // ALL waves done reading WgT before obuf overwrites it

    const float4* boxp4 = reinterpret_cast<const float4*>(boxp);
    const size_t plane = (size_t)NNq * NNq;

    const int base4 = (blockIdx.x * 4 + wid) * 4;   // 4 consecutive slabs per wave
#pragma unroll
    for (int it = 0; it < 4; ++it) {
        const int slab = base4 + it;
        const int p0 = slab << 4;
        const int b  = p0 >> 18;
        const int rem = p0 & (NNq * NNq - 1);
        const int i  = rem >> 9;
        const int j0 = rem & (NNq - 1);

        float4 bi = boxp4[b * NNq + i];
        float4 bj = boxp4[b * NNq + j0 + ln15];
        float rel[4];
        rel[0] = __logf(fabsf(bj.x - bi.x) / bj.z + EPSF);
        rel[1] = __logf(fabsf(bj.y - bi.y) / bj.w + EPSF);
        rel[2] = __logf(bi.z / bj.z + EPSF);
        rel[3] = __logf(bi.w / bj.w + EPSF);

        f32x4 acc0 = {0.f, 0.f, 0.f, 0.f};
        f32x4 acc1 = {0.f, 0.f, 0.f, 0.f};

#pragma unroll
        for (int kc2 = 0; kc2 < 4; ++kc2) {
            const float rc = rel[kc2];
            f16x8 afs, afc;
#pragma unroll
            for (int j = 0; j < 8; ++j) {
                float rv = FRACTF(rc * invd[j]);
                afs[j] = (_Float16)SINR(rv);
                afc[j] = (_Float16)COSR(rv);
            }
            acc0 = __builtin_amdgcn_mfma_f32_16x16x32_f16(afs, bS0[kc2], acc0, 0, 0, 0);
            acc0 = __builtin_amdgcn_mfma_f32_16x16x32_f16(afc, bC0[kc2], acc0, 0, 0, 0);
            acc1 = __builtin_amdgcn_mfma_f32_16x16x32_f16(afs, bS1[kc2], acc1, 0, 0, 0);
            acc1 = __builtin_amdgcn_mfma_f32_16x16x32_f16(afc, bC1[kc2], acc1, 0, 0, 0);
        }

#pragma unroll
        for (int r = 0; r < 4; ++r) {
            const int m = it * 16 + (kgrp << 2) + r;    // j within the 64-run
            float g0 = fmaxf(acc0[r] + bg0, 0.f);
            obuf[wid][n0][m] = __float2half(g0);
            if (n1 < 24) {
                float g1 = fmaxf(acc1[r] + bg1, 0.f);
                obuf[wid][n1][m] = __float2half(g1);
            }
        }
    }
    __syncthreads();

    // coalesced write-out with log+mask fold: 24 rows of 64 contiguous halfs
    const int b_  = base4 >> 14;
    const int i_  = (base4 >> 5) & (NNq - 1);
    const int j0b = (base4 & 31) << 4;
    const int mv  = maskp[((size_t)b_ * NNq + i_) * NNq + j0b + lane];
    size_t obase = (size_t)b_ * plane + (size_t)i_ * NNq + j0b + lane;
#pragma unroll
    for (int t = 0; t < 24; ++t) {
        float g = __half2float(obuf[wid][t][lane]);
        float v = (mv != 0) ? __logf(g + 1e-6f) : -60000.0f;
        lg[obase + (size_t)t * (BB * plane)] = __float2half(v);
    }
}

// ---------------------------------------------------------------- GEMM (MFMA fp16)
// Round-9: tile 32(M) x 64(N) (was 64x64) -> qkv grid 384, o grid 128 blocks
// (was 192/64; o-proj left 75% of CUs idle). Wave w: m-sub (w&1), n-subs
// {(w>>1)*16, (w>>1)*16+32}.
#define LDP 264
__global__ __launch_bounds__(256) void k_gemm_mfma(const float* __restrict__ A,
        const float* __restrict__ W0, const float* __restrict__ W1, const float* __restrict__ W2,
        const float* __restrict__ b0, const float* __restrict__ b1, const float* __restrict__ b2,
        float* __restrict__ C0, float* __restrict__ C1, float* __restrict__ C2,
        const float* __restrict__ resid) {
    const float* W   = (blockIdx.z == 0) ? W0 : (blockIdx.z == 1) ? W1 : W2;
    const float* bia = (blockIdx.z == 0) ? b0 : (blockIdx.z == 1) ? b1 : b2;
    float*       C   = (blockIdx.z == 0) ? C0 : (blockIdx.z == 1) ? C1 : C2;

    __shared__ _Float16 As[32 * LDP];   // [m][k] fp16, padded
    __shared__ _Float16 Ws[64 * LDP];   // [n][k] fp16 (W transposed), padded

    const int tid = threadIdx.x;
    const int m0 = blockIdx.x * 32, n0 = blockIdx.y * 64;

    for (int u = tid; u < 32 * 64; u += 256) {          // A: float4 units
        int m = u >> 6, k4 = (u & 63) * 4;
        float4 av = *reinterpret_cast<const float4*>(&A[(size_t)(m0 + m) * 256 + k4]);
        f16x4 hv = {(_Float16)av.x, (_Float16)av.y, (_Float16)av.z, (_Float16)av.w};
        *reinterpret_cast<f16x4*>(&As[m * LDP + k4]) = hv;
    }
    for (int u = tid; u < 64 * 64; u += 256) {          // W transposed
        int n = u & 63, k4 = (u >> 6) * 4;
        f16x4 hv = {(_Float16)W[(size_t)(k4 + 0) * 256 + n0 + n],
                    (_Float16)W[(size_t)(k4 + 1) * 256 + n0 + n],
                    (_Float16)W[(size_t)(k4 + 2) * 256 + n0 + n],
                    (_Float16)W[(size_t)(k4 + 3) * 256 + n0 + n]};
        *reinterpret_cast<f16x4*>(&Ws[n * LDP + k4]) = hv;
    }
    __syncthreads();

    const int lane = tid & 63;
    const int wid  = tid >> 6;
    const int ln15 = lane & 15;
    const int kgrp = lane >> 4;
    const int mw   = (wid & 1) * 16;
    const int nsel = (wid >> 1) * 16;
    const int kfr  = kgrp * 8;

    f32x4 acc[2] = {{0.f,0.f,0.f,0.f},{0.f,0.f,0.f,0.f}};
#pragma unroll
    for (int kc = 0; kc < 8; ++kc) {
        f16x8 af = *reinterpret_cast<const f16x8*>(&As[(mw + ln15) * LDP + kc * 32 + kfr]);
#pragma unroll
        for (int t = 0; t < 2; ++t) {
            f16x8 bf = *reinterpret_cast<const f16x8*>(
                &Ws[(nsel + t * 32 + ln15) * LDP + kc * 32 + kfr]);
            acc[t] = __builtin_amdgcn_mfma_f32_16x16x32_f16(af, bf, acc[t], 0, 0, 0);
        }
    }

#pragma unroll
    for (int t = 0; t < 2; ++t) {
        const int col = n0 + nsel + t * 32 + ln15;
        const float bv = bia[col];
#pragma unroll
        for (int r = 0; r < 4; ++r) {
            const int row = m0 + mw + kgrp * 4 + r;
            float o = fmaxf(acc[t][r] + bv, 0.f);
            if (resid) o += resid[(size_t)row * 256 + col];
            C[(size_t)row * 256 + col] = o;
        }
    }
}

// ---------------------------------------------------------------- fused attention
// Round-9: q-tile 16 rows (was 32) -> grid 512 blocks = 2 blocks/CU = 8
// waves/CU (was 1 block/CU, 12.5% occupancy). Same proven VALU structure,
// same math. S phase: 2 rows x 4 j per thread; PV: 1 row x 2 d.
__global__ __launch_bounds__(256) void k_attn(const float* __restrict__ q,
                                              const float* __restrict__ kk,
                                              const float* __restrict__ vv,
                                              const __half* __restrict__ lg,
                                              float* __restrict__ y, int l) {
    const int bh = blockIdx.y;
    const int b = bh >> 3, h = bh & 7;
    const int i0t = blockIdx.x * 16;

    __shared__ float Qs[16][36];
    __shared__ float Kst[32][132];   // [d][j] transposed
    __shared__ float Vs[128][36];
    __shared__ float Ps[16][132];
    __shared__ float rowc[16], rowl[16];

    const int tid = threadIdx.x;
    const int tx = tid & 31, ty = tid >> 5;
    const int si0 = ty * 2, sj0 = tx * 4;
    const int prow = tid >> 4, pd2 = (tid & 15) * 2;

    if (tid < 128) {   // load Q tile (16 x 32)
        int i = tid >> 3, d4 = (tid & 7) * 4;
        *reinterpret_cast<float4*>(&Qs[i][d4]) = *reinterpret_cast<const float4*>(
            &q[(size_t)(b * NNq + i0t + i) * DDm + h * DHh + d4]);
    }

    float m_r[2], l_r[2];
#pragma unroll
    for (int e = 0; e < 2; ++e) { m_r[e] = -3.0e38f; l_r[e] = 0.f; }
    float oa0 = 0.f, oa1 = 0.f;

    const size_t plane = (size_t)NNq * NNq;
    const size_t lg_base = (size_t)((l * 8 + h) * BB + b) * plane;

    for (int jb = 0; jb < 4; ++jb) {
        const int j0t = jb * 128;
        __syncthreads();
#pragma unroll
        for (int r = 0; r < 4; ++r) {   // K transposed
            int idx = r * 256 + tid;
            int j = idx >> 3, d4 = (idx & 7) * 4;
            float4 kv = *reinterpret_cast<const float4*>(
                &kk[(size_t)(b * NNq + j0t + j) * DDm + h * DHh + d4]);
            Kst[d4 + 0][j] = kv.x; Kst[d4 + 1][j] = kv.y;
            Kst[d4 + 2][j] = kv.z; Kst[d4 + 3][j] = kv.w;
        }
#pragma unroll
        for (int r = 0; r < 4; ++r) {   // V
            int idx = r * 256 + tid;
            int j = idx >> 3, d4 = (idx & 7) * 4;
            *reinterpret_cast<float4*>(&Vs[j][d4]) = *reinterpret_cast<const float4*>(
                &vv[(size_t)(b * NNq + j0t + j) * DDm + h * DHh + d4]);
        }
        __syncthreads();

        float acc[2][4] = {};
#pragma unroll 8
        for (int d = 0; d < 32; ++d) {
            float4 kv = *reinterpret_cast<const float4*>(&Kst[d][sj0]);
#pragma unroll
            for (int e = 0; e < 2; ++e) {
                float a = Qs[si0 + e][d];
                acc[e][0] = fmaf(a, kv.x, acc[e][0]);
                acc[e][1] = fmaf(a, kv.y, acc[e][1]);
                acc[e][2] = fmaf(a, kv.z, acc[e][2]);
                acc[e][3] = fmaf(a, kv.w, acc[e][3]);
            }
        }

#pragma unroll
        for (int e = 0; e < 2; ++e) {
            int ig = i0t + si0 + e;
            int jg = j0t + sj0;
            H4 g4 = *reinterpret_cast<const H4*>(&lg[lg_base + (size_t)ig * NNq + jg]);
            float4 sv;
            sv.x = acc[e][0] * SCALE + __half2float(g4.a);
            sv.y = acc[e][1] * SCALE + __half2float(g4.b);
            sv.z = acc[e][2] * SCALE + __half2float(g4.c);
            sv.w = acc[e][3] * SCALE + __half2float(g4.d);

            float mx = fmaxf(fmaxf(sv.x, sv.y), fmaxf(sv.z, sv.w));
#pragma unroll
            for (int o = 16; o > 0; o >>= 1) mx = fmaxf(mx, __shfl_xor(mx, o, 32));
            float mnew = fmaxf(m_r[e], mx);
            float c = __expf(m_r[e] - mnew);
            sv.x = __expf(sv.x - mnew); sv.y = __expf(sv.y - mnew);
            sv.z = __expf(sv.z - mnew); sv.w = __expf(sv.w - mnew);
            float s4 = sv.x + sv.y + sv.z + sv.w;
#pragma unroll
            for (int o = 16; o > 0; o >>= 1) s4 += __shfl_xor(s4, o, 32);
            l_r[e] = l_r[e] * c + s4;
            m_r[e] = mnew;
            *reinterpret_cast<float4*>(&Ps[si0 + e][sj0]) = sv;
            if (tx == 0) rowc[si0 + e] = c;
        }
        __syncthreads();

        float cr = rowc[prow];
        oa0 *= cr; oa1 *= cr;
#pragma unroll 8
        for (int j = 0; j < 128; j += 4) {
            float4 p4 = *reinterpret_cast<const float4*>(&Ps[prow][j]);
            float2 v0 = *reinterpret_cast<const float2*>(&Vs[j + 0][pd2]);
            float2 v1 = *reinterpret_cast<const float2*>(&Vs[j + 1][pd2]);
            float2 v2 = *reinterpret_cast<const float2*>(&Vs[j + 2][pd2]);
            float2 v3 = *reinterpret_cast<const float2*>(&Vs[j + 3][pd2]);
            oa0 = fmaf(p4.x, v0.x, oa0); oa1 = fmaf(p4.x, v0.y, oa1);
            oa0 = fmaf(p4.y, v1.x, oa0); oa1 = fmaf(p4.y, v1.y, oa1);
            oa0 = fmaf(p4.z, v2.x, oa0); oa1 = fmaf(p4.z, v2.y, oa1);
            oa0 = fmaf(p4.w, v3.x, oa0); oa1 = fmaf(p4.w, v3.y, oa1);
        }
    }

    if (tx == 0) {
#pragma unroll
        for (int e = 0; e < 2; ++e) rowl[si0 + e] = l_r[e];
    }
    __syncthreads();
    float inv = 1.0f / rowl[prow];
    float2 ov = make_float2(oa0 * inv, oa1 * inv);
    *reinterpret_cast<float2*>(&y[(size_t)(b * NNq + i0t + prow) * DDm + h * DHh + pd2]) = ov;
}

// ---------------------------------------------------------------- launch
extern "C" void kernel_launch(void* const* d_in, const int* in_sizes, int n_in,
                              void* d_out, int out_size, void* d_ws, size_t ws_size,
                              hipStream_t stream) {
    const float* boxes    = (const float*)d_in[0];
    const float* features = (const float*)d_in[1];
    const int*   mask     = (const int*)d_in[2];
    const float* Wq = (const float*)d_in[3];
    const float* bq = (const float*)d_in[4];
    const float* Wk = (const float*)d_in[5];
    const float* bk = (const float*)d_in[6];
    const float* Wv = (const float*)d_in[7];
    const float* bv = (const float*)d_in[8];
    const float* Wo = (const float*)d_in[9];
    const float* bo = (const float*)d_in[10];
    const float* Wg = (const float*)d_in[11];
    const float* bg = (const float*)d_in[12];
    const float* dv = (const float*)d_in[13];

    char* ws = (char*)d_ws;
    float*  boxp = (float*)(ws);                              //    16,384
    __half* lg   = (__half*)(ws + 16384);                     // 25,165,824
    float*  qb   = (float*)(ws + 25182208);                   //  1,048,576
    float*  kb   = (float*)(ws + 26230784);                   //  1,048,576
    float*  vb   = (float*)(ws + 27279360);                   //  1,048,576
    float*  yb   = (float*)(ws + 28327936);                   //  1,048,576  -> ~29.4 MB
    float*  x    = (float*)d_out;

    k_boxprep<<<dim3((BB * NNq + 255) / 256), dim3(256), 0, stream>>>(boxes, boxp);
    k_geo<<<dim3(2048), dim3(256), 0, stream>>>(boxp, Wg, bg, dv, mask, lg);

    for (int l = 0; l < LLn; ++l) {
        const float* Wq_l = Wq + (size_t)l * DDm * DDm;
        const float* Wk_l = Wk + (size_t)l * DDm * DDm;
        const float* Wv_l = Wv + (size_t)l * DDm * DDm;
        const float* Wo_l = Wo + (size_t)l * DDm * DDm;
        const float* bq_l = bq + (size_t)l * DDm;
        const float* bk_l = bk + (size_t)l * DDm;
        const float* bv_l = bv + (size_t)l * DDm;
        const float* bo_l = bo + (size_t)l * DDm;
        const float* xin  = (l == 0) ? features : x;   // layer-0 reads features directly

        k_gemm_mfma<<<dim3(32, 4, 3), dim3(256), 0, stream>>>(
            xin, Wq_l, Wk_l, Wv_l, bq_l, bk_l, bv_l, qb, kb, vb, nullptr);
        k_attn<<<dim3(32, 16), dim3(256), 0, stream>>>(qb, kb, vb, lg, yb, l);
        k_gemm_mfma<<<dim3(32, 4, 1), dim3(256), 0, stream>>>(
            yb, Wo_l, Wo_l, Wo_l, bo_l, bo_l, bo_l, x, x, x, xin);
    }
}

// Round 11
// 157.594 us; speedup vs baseline: 1.6092x; 1.2605x over previous
//
#include <hip/hip_runtime.h>
#include <hip/hip_fp16.h>

// Problem constants (from reference): B=2, N=512, D=256, H=8, L=3
#define BB 2
#define NNq 512
#define DDm 256
#define HHh 8
#define DHh 32
#define LLn 3

static constexpr float EPSF   = 1e-4f;
static constexpr float INV2PI = 0.15915494309189535f;   // 1/(2*pi)
static constexpr float SCALE  = 0.17677669529663687f;   // 1/sqrt(32)

#if __has_builtin(__builtin_amdgcn_fractf)
#define FRACTF(x) __builtin_amdgcn_fractf(x)
#else
#define FRACTF(x) ((x) - floorf(x))
#endif
#if __has_builtin(__builtin_amdgcn_sinf)
#define SINR(x) __builtin_amdgcn_sinf(x)   // sin(2*pi*x), x in revolutions
#define COSR(x) __builtin_amdgcn_cosf(x)
#else
#define SINR(x) __sinf((x) * 6.2831853071795865f)
#define COSR(x) __cosf((x) * 6.2831853071795865f)
#endif

typedef _Float16 f16x8 __attribute__((ext_vector_type(8)));
typedef _Float16 f16x4 __attribute__((ext_vector_type(4)));
typedef _Float16 f16x2 __attribute__((ext_vector_type(2)));
typedef float    f32x4 __attribute__((ext_vector_type(4)));

__device__ inline f16x2 pk2(float a, float b) {
#if __has_builtin(__builtin_amdgcn_cvt_pkrtz)
    return __builtin_bit_cast(f16x2, __builtin_amdgcn_cvt_pkrtz(a, b));
#else
    f16x2 r; r[0] = (_Float16)a; r[1] = (_Float16)b; return r;
#endif
}
union U16x8 { f16x8 v; f16x2 h[4]; };
union U16x4 { f16x4 v; f16x2 h[2]; };

// ---------------------------------------------------------------- geo (MFMA, fp16)
// Round-11 (= round-10 + compile fix): boxprep folded inline; A-fragment fp16
// packing via cvt_pkrtz. Structure otherwise the round-9 plateau version.
__global__ __launch_bounds__(256) void k_geo(const float* __restrict__ boxes,
                                             const float* __restrict__ Wg,
                                             const float* __restrict__ bg,
                                             const float* __restrict__ divm,
                                             const int* __restrict__ maskp,
                                             __half* __restrict__ lg) {
    __shared__ char smem[16384];     // union: WgT (16384B) then obuf (13056B)
    _Float16* WgT = reinterpret_cast<_Float16*>(smem);          // [32][256]
    __half (*obuf)[24][68] = reinterpret_cast<__half (*)[24][68]>(smem);

    const int tid = threadIdx.x;
    for (int idx = tid; idx < 32 * 256; idx += 256) {
        int n = idx >> 8, k = idx & 255;
        float w = (n < 24) ? Wg[(size_t)(n >> 3) * 2048 + (size_t)k * 8 + (n & 7)] : 0.f;
        WgT[n * 256 + (k ^ ((n & 7) << 3))] = (_Float16)w;
    }
    __syncthreads();

    const int lane = tid & 63;
    const int wid  = tid >> 6;
    const int ln15 = lane & 15;
    const int kgrp = lane >> 4;          // 0..3

    float invd[8];
    {
        const float4* dv4 = reinterpret_cast<const float4*>(divm);
        float4 da = dv4[kgrp * 2], db = dv4[kgrp * 2 + 1];
        invd[0] = INV2PI / da.x; invd[1] = INV2PI / da.y;
        invd[2] = INV2PI / da.z; invd[3] = INV2PI / da.w;
        invd[4] = INV2PI / db.x; invd[5] = INV2PI / db.y;
        invd[6] = INV2PI / db.z; invd[7] = INV2PI / db.w;
    }
    const int n0 = ln15;            // output col, tile 0 (always < 24)
    const int n1 = 16 + ln15;       // output col, tile 1 (valid if < 24)
    const float bg0 = bg[n0];
    const float bg1 = (n1 < 24) ? bg[n1] : 0.f;

    // swizzle involution split into disjoint bit-fields (round-4 fix)
    const int mask  = (ln15 & 7) << 3;          // bits 3..5
    const int flip5 = mask & 32;                // bit 5 -> flips kc low bit
    const int kb    = (kgrp << 3) ^ (mask & 24);
    const int base0 = n0 * 256 + kb;
    const int base1 = n1 * 256 + kb;

    // hoist loop-invariant B-fragments into registers (WgT dead afterwards)
    f16x8 bS0[4], bC0[4], bS1[4], bC1[4];
#pragma unroll
    for (int kc2 = 0; kc2 < 4; ++kc2) {
        const int koffS = ((2 * kc2) * 32) ^ flip5;
        const int koffC = ((2 * kc2 + 1) * 32) ^ flip5;
        bS0[kc2] = *reinterpret_cast<const f16x8*>(&WgT[base0 + koffS]);
        bC0[kc2] = *reinterpret_cast<const f16x8*>(&WgT[base0 + koffC]);
        bS1[kc2] = *reinterpret_cast<const f16x8*>(&WgT[base1 + koffS]);
        bC1[kc2] = *reinterpret_cast<const f16x8*>(&WgT[base1 + koffC]);
    }
    __syncthreads();   // ALL waves done reading WgT before obuf overwrites it

    const float4* boxes4 = reinterpret_cast<const float4*>(boxes);
    const size_t plane = (size_t)NNq * NNq;

    const int base4 = (blockIdx.x * 4 + wid) * 4;   // 4 consecutive slabs per wave
#pragma unroll
    for (int it = 0; it < 4; ++it) {
        const int slab = base4 + it;
        const int p0 = slab << 4;
        const int b  = p0 >> 18;
        const int rem = p0 & (NNq * NNq - 1);
        const int i  = rem >> 9;
        const int j0 = rem & (NNq - 1);

        float4 Bi = boxes4[b * NNq + i];
        float4 Bj = boxes4[b * NNq + j0 + ln15];
        float cxi = 0.5f * (Bi.x + Bi.z), cyi = 0.5f * (Bi.y + Bi.w);
        float wi  = fmaxf(Bi.z - Bi.x, EPSF), hi = fmaxf(Bi.w - Bi.y, EPSF);
        float cxj = 0.5f * (Bj.x + Bj.z), cyj = 0.5f * (Bj.y + Bj.w);
        float wj  = fmaxf(Bj.z - Bj.x, EPSF), hj = fmaxf(Bj.w - Bj.y, EPSF);
        float rel[4];
        rel[0] = __logf(fabsf(cxj - cxi) / wj + EPSF);
        rel[1] = __logf(fabsf(cyj - cyi) / hj + EPSF);
        rel[2] = __logf(wi / wj + EPSF);
        rel[3] = __logf(hi / hj + EPSF);

        f32x4 acc0 = {0.f, 0.f, 0.f, 0.f};
        f32x4 acc1 = {0.f, 0.f, 0.f, 0.f};

#pragma unroll
        for (int kc2 = 0; kc2 < 4; ++kc2) {
            const float rc = rel[kc2];
            U16x8 afs, afc;
#pragma unroll
            for (int jj = 0; jj < 4; ++jj) {
                float rv0 = FRACTF(rc * invd[2 * jj]);
                float rv1 = FRACTF(rc * invd[2 * jj + 1]);
                afs.h[jj] = pk2(SINR(rv0), SINR(rv1));
                afc.h[jj] = pk2(COSR(rv0), COSR(rv1));
            }
            acc0 = __builtin_amdgcn_mfma_f32_16x16x32_f16(afs.v, bS0[kc2], acc0, 0, 0, 0);
            acc0 = __builtin_amdgcn_mfma_f32_16x16x32_f16(afc.v, bC0[kc2], acc0, 0, 0, 0);
            acc1 = __builtin_amdgcn_mfma_f32_16x16x32_f16(afs.v, bS1[kc2], acc1, 0, 0, 0);
            acc1 = __builtin_amdgcn_mfma_f32_16x16x32_f16(afc.v, bC1[kc2], acc1, 0, 0, 0);
        }

#pragma unroll
        for (int r = 0; r < 4; ++r) {
            const int m = it * 16 + (kgrp << 2) + r;    // j within the 64-run
            float g0 = fmaxf(acc0[r] + bg0, 0.f);
            obuf[wid][n0][m] = __float2half(g0);
            if (n1 < 24) {
                float g1 = fmaxf(acc1[r] + bg1, 0.f);
                obuf[wid][n1][m] = __float2half(g1);
            }
        }
    }
    __syncthreads();

    // coalesced write-out with log+mask fold: 24 rows of 64 contiguous halfs
    const int b_  = base4 >> 14;
    const int i_  = (base4 >> 5) & (NNq - 1);
    const int j0b = (base4 & 31) << 4;
    const int mv  = maskp[((size_t)b_ * NNq + i_) * NNq + j0b + lane];
    size_t obase = (size_t)b_ * plane + (size_t)i_ * NNq + j0b + lane;
#pragma unroll
    for (int t = 0; t < 24; ++t) {
        float g = __half2float(obuf[wid][t][lane]);
        float v = (mv != 0) ? __logf(g + 1e-6f) : -60000.0f;
        lg[obase + (size_t)t * (BB * plane)] = __float2half(v);
    }
}

// ---------------------------------------------------------------- GEMM (MFMA fp16)
// tile 32(M) x 64(N); unchanged from round 9 (verified).
#define LDP 264
__global__ __launch_bounds__(256) void k_gemm_mfma(const float* __restrict__ A,
        const float* __restrict__ W0, const float* __restrict__ W1, const float* __restrict__ W2,
        const float* __restrict__ b0, const float* __restrict__ b1, const float* __restrict__ b2,
        float* __restrict__ C0, float* __restrict__ C1, float* __restrict__ C2,
        const float* __restrict__ resid) {
    const float* W   = (blockIdx.z == 0) ? W0 : (blockIdx.z == 1) ? W1 : W2;
    const float* bia = (blockIdx.z == 0) ? b0 : (blockIdx.z == 1) ? b1 : b2;
    float*       C   = (blockIdx.z == 0) ? C0 : (blockIdx.z == 1) ? C1 : C2;

    __shared__ _Float16 As[32 * LDP];   // [m][k] fp16, padded
    __shared__ _Float16 Ws[64 * LDP];   // [n][k] fp16 (W transposed), padded

    const int tid = threadIdx.x;
    const int m0 = blockIdx.x * 32, n0 = blockIdx.y * 64;

    for (int u = tid; u < 32 * 64; u += 256) {          // A: float4 units
        int m = u >> 6, k4 = (u & 63) * 4;
        float4 av = *reinterpret_cast<const float4*>(&A[(size_t)(m0 + m) * 256 + k4]);
        f16x4 hv = {(_Float16)av.x, (_Float16)av.y, (_Float16)av.z, (_Float16)av.w};
        *reinterpret_cast<f16x4*>(&As[m * LDP + k4]) = hv;
    }
    for (int u = tid; u < 64 * 64; u += 256) {          // W transposed
        int n = u & 63, k4 = (u >> 6) * 4;
        f16x4 hv = {(_Float16)W[(size_t)(k4 + 0) * 256 + n0 + n],
                    (_Float16)W[(size_t)(k4 + 1) * 256 + n0 + n],
                    (_Float16)W[(size_t)(k4 + 2) * 256 + n0 + n],
                    (_Float16)W[(size_t)(k4 + 3) * 256 + n0 + n]};
        *reinterpret_cast<f16x4*>(&Ws[n * LDP + k4]) = hv;
    }
    __syncthreads();

    const int lane = tid & 63;
    const int wid  = tid >> 6;
    const int ln15 = lane & 15;
    const int kgrp = lane >> 4;
    const int mw   = (wid & 1) * 16;
    const int nsel = (wid >> 1) * 16;
    const int kfr  = kgrp * 8;

    f32x4 acc[2] = {{0.f,0.f,0.f,0.f},{0.f,0.f,0.f,0.f}};
#pragma unroll
    for (int kc = 0; kc < 8; ++kc) {
        f16x8 af = *reinterpret_cast<const f16x8*>(&As[(mw + ln15) * LDP + kc * 32 + kfr]);
#pragma unroll
        for (int t = 0; t < 2; ++t) {
            f16x8 bf = *reinterpret_cast<const f16x8*>(
                &Ws[(nsel + t * 32 + ln15) * LDP + kc * 32 + kfr]);
            acc[t] = __builtin_amdgcn_mfma_f32_16x16x32_f16(af, bf, acc[t], 0, 0, 0);
        }
    }

#pragma unroll
    for (int t = 0; t < 2; ++t) {
        const int col = n0 + nsel + t * 32 + ln15;
        const float bv = bia[col];
#pragma unroll
        for (int r = 0; r < 4; ++r) {
            const int row = m0 + mw + kgrp * 4 + r;
            float o = fmaxf(acc[t][r] + bv, 0.f);
            if (resid) o += resid[(size_t)row * 256 + col];
            C[(size_t)row * 256 + col] = o;
        }
    }
}

// ---------------------------------------------------------------- fused attention (MFMA v2)
// Block = (b,h) x 16 q-rows, 4 waves. Stage K[512][32] + V^T[32][512] fp16 in
// LDS ONCE (XOR-swizzled, byte ^= ((row&7)<<4), same involution both sides).
// Wave w owns j-slice [w*128, w*128+128): 8 QK^T MFMAs (Q-frag in registers),
// ONE-SHOT softmax over the slice (no online rescale), P -> wave-private LDS
// (no barrier), 8 PV MFMAs. Cross-wave flash-combine at the end: partials
// (O,m,l) alias each wave's dead K-slab. Only 2 barriers per block.
__global__ __launch_bounds__(256) void k_attn(const float* __restrict__ q,
                                              const float* __restrict__ kk,
                                              const float* __restrict__ vv,
                                              const __half* __restrict__ lg,
                                              float* __restrict__ y, int l) {
    __shared__ _Float16 Kh[512 * 32];   // 32 KB, row j: 64B, swz ((j&7)<<4)
    __shared__ _Float16 VT[32 * 512];   // 32 KB, row d: 1KB, swz ((d&7)<<4)
    __shared__ _Float16 Ps[4][16 * 128];// 16 KB, per-wave [i][jloc], swz ((i&7)<<4)

    const int bh = blockIdx.y;
    const int b = bh >> 3, h = bh & 7;
    const int i0t = blockIdx.x * 16;

    const int tid  = threadIdx.x;
    const int lane = tid & 63, wid = tid >> 6;
    const int ln15 = lane & 15, kgrp = lane >> 4;

    // stage K and V (fp32 -> fp16), coalesced reads
    for (int u = tid; u < 4096; u += 256) {
        int j = u >> 3, d4 = (u & 7) * 4;
        const size_t src = (size_t)(b * NNq + j) * DDm + h * DHh + d4;
        float4 kv = *reinterpret_cast<const float4*>(&kk[src]);
        U16x4 hk; hk.h[0] = pk2(kv.x, kv.y); hk.h[1] = pk2(kv.z, kv.w);
        *reinterpret_cast<f16x4*>(reinterpret_cast<char*>(Kh) +
            (((j * 64 + d4 * 2)) ^ ((j & 7) << 4))) = hk.v;
        float4 v4 = *reinterpret_cast<const float4*>(&vv[src]);
        float ve[4] = {v4.x, v4.y, v4.z, v4.w};
#pragma unroll
        for (int e = 0; e < 4; ++e) {
            int row = d4 + e;
            *reinterpret_cast<_Float16*>(reinterpret_cast<char*>(VT) +
                (((row * 1024 + j * 2)) ^ ((row & 7) << 4))) = (_Float16)ve[e];
        }
    }

    // Q-fragment in registers (loop-invariant): lane ln15 = row i, kgrp*8 k-slice
    U16x8 qf;
    {
        const float* qp = &q[(size_t)(b * NNq + i0t + ln15) * DDm + h * DHh + kgrp * 8];
        float4 q0 = *reinterpret_cast<const float4*>(qp);
        float4 q1 = *reinterpret_cast<const float4*>(qp + 4);
        qf.h[0] = pk2(q0.x, q0.y); qf.h[1] = pk2(q0.z, q0.w);
        qf.h[2] = pk2(q1.x, q1.y); qf.h[3] = pk2(q1.z, q1.w);
    }
    __syncthreads();

    const int jbase = wid * 128;
    const size_t plane = (size_t)NNq * NNq;
    const size_t lg_base = (size_t)((l * 8 + h) * BB + b) * plane;

    // QK^T: 8 MFMAs -> lane holds S[i=kgrp*4+r][j=jbase+t*16+ln15]
    f32x4 s[8];
#pragma unroll
    for (int t = 0; t < 8; ++t) {
        int j = jbase + t * 16 + ln15;
        f16x8 kf = *reinterpret_cast<const f16x8*>(reinterpret_cast<char*>(Kh) +
            (((j * 64 + kgrp * 16)) ^ ((j & 7) << 4)));
        f32x4 z = {0.f, 0.f, 0.f, 0.f};
        s[t] = __builtin_amdgcn_mfma_f32_16x16x32_f16(qf.v, kf, z, 0, 0, 0);
    }

    // scale + lg (log(geo)+mask prefolded)
#pragma unroll
    for (int t = 0; t < 8; ++t) {
        const size_t jg = jbase + t * 16 + ln15;
#pragma unroll
        for (int r = 0; r < 4; ++r) {
            float lgv = __half2float(lg[lg_base + (size_t)(i0t + kgrp * 4 + r) * NNq + jg]);
            s[t][r] = s[t][r] * SCALE + lgv;
        }
    }

    // one-shot softmax over the wave's 128-j slice (rows reduce across ln15)
    float m_[4], l_[4];
#pragma unroll
    for (int r = 0; r < 4; ++r) {
        float mx = s[0][r];
#pragma unroll
        for (int t = 1; t < 8; ++t) mx = fmaxf(mx, s[t][r]);
#pragma unroll
        for (int o = 1; o < 16; o <<= 1) mx = fmaxf(mx, __shfl_xor(mx, o, 64));
        float sum = 0.f;
#pragma unroll
        for (int t = 0; t < 8; ++t) {
            float p = __expf(s[t][r] - mx);
            s[t][r] = p; sum += p;
        }
#pragma unroll
        for (int o = 1; o < 16; o <<= 1) sum += __shfl_xor(sum, o, 64);
        m_[r] = mx; l_[r] = sum;
    }

    // P -> wave-private LDS (fp16, swizzled); no barrier needed
    {
        char* psb = reinterpret_cast<char*>(Ps[wid]);
#pragma unroll
        for (int r = 0; r < 4; ++r) {
            const int row = kgrp * 4 + r;
            const int rb = row * 256, sw = (row & 7) << 4;
#pragma unroll
            for (int t = 0; t < 8; ++t) {
                int byte = (rb + (t * 16 + ln15) * 2) ^ sw;
                *reinterpret_cast<_Float16*>(psb + byte) = (_Float16)s[t][r];
            }
        }
    }

    // PV: 4 j-chunks x 2 d-tiles; O[i=kgrp*4+r][d=dt*16+ln15]
    f32x4 oacc[2] = {{0.f,0.f,0.f,0.f},{0.f,0.f,0.f,0.f}};
    {
        char* psb = reinterpret_cast<char*>(Ps[wid]);
#pragma unroll
        for (int kc = 0; kc < 4; ++kc) {
            f16x8 pf = *reinterpret_cast<const f16x8*>(psb +
                ((ln15 * 256 + kc * 64 + kgrp * 16) ^ ((ln15 & 7) << 4)));
#pragma unroll
            for (int dt = 0; dt < 2; ++dt) {
                int d = dt * 16 + ln15;
                f16x8 vf = *reinterpret_cast<const f16x8*>(reinterpret_cast<char*>(VT) +
                    ((d * 1024 + (jbase + kc * 32 + kgrp * 8) * 2) ^ ((d & 7) << 4)));
                oacc[dt] = __builtin_amdgcn_mfma_f32_16x16x32_f16(pf, vf, oacc[dt], 0, 0, 0);
            }
        }
    }

    // write partials into this wave's (dead) K slab: [16][32] O + m[16] + l[16]
    {
        float* Op = reinterpret_cast<float*>(reinterpret_cast<char*>(Kh) + wid * 8192);
#pragma unroll
        for (int dt = 0; dt < 2; ++dt)
#pragma unroll
            for (int r = 0; r < 4; ++r)
                Op[(kgrp * 4 + r) * 32 + dt * 16 + ln15] = oacc[dt][r];
        if (ln15 == 0) {
#pragma unroll
            for (int r = 0; r < 4; ++r) {
                Op[512 + kgrp * 4 + r] = m_[r];
                Op[528 + kgrp * 4 + r] = l_[r];
            }
        }
    }
    __syncthreads();

    // flash-combine across 4 waves; thread -> (i = tid>>4, d0 = (tid&15)*2)
    {
        const int i = tid >> 4, d0 = (tid & 15) * 2;
        float mw[4], M = -3.0e38f;
#pragma unroll
        for (int w = 0; w < 4; ++w) {
            mw[w] = reinterpret_cast<float*>(reinterpret_cast<char*>(Kh) + w * 8192)[512 + i];
            M = fmaxf(M, mw[w]);
        }
        float o0 = 0.f, o1 = 0.f, ls = 0.f;
#pragma unroll
        for (int w = 0; w < 4; ++w) {
            float* Op = reinterpret_cast<float*>(reinterpret_cast<char*>(Kh) + w * 8192);
            float sc = __expf(mw[w] - M);
            ls += Op[528 + i] * sc;
            o0 += Op[i * 32 + d0] * sc;
            o1 += Op[i * 32 + d0 + 1] * sc;
        }
        float inv = 1.0f / ls;
        *reinterpret_cast<float2*>(&y[(size_t)(b * NNq + i0t + i) * DDm + h * DHh + d0]) =
            make_float2(o0 * inv, o1 * inv);
    }
}

// ---------------------------------------------------------------- launch
extern "C" void kernel_launch(void* const* d_in, const int* in_sizes, int n_in,
                              void* d_out, int out_size, void* d_ws, size_t ws_size,
                              hipStream_t stream) {
    const float* boxes    = (const float*)d_in[0];
    const float* features = (const float*)d_in[1];
    const int*   mask     = (const int*)d_in[2];
    const float* Wq = (const float*)d_in[3];
    const float* bq = (const float*)d_in[4];
    const float* Wk = (const float*)d_in[5];
    const float* bk = (const float*)d_in[6];
    const float* Wv = (const float*)d_in[7];
    const float* bv = (const float*)d_in[8];
    const float* Wo = (const float*)d_in[9];
    const float* bo = (const float*)d_in[10];
    const float* Wg = (const float*)d_in[11];
    const float* bg = (const float*)d_in[12];
    const float* dv = (const float*)d_in[13];

    char* ws = (char*)d_ws;
    __half* lg   = (__half*)(ws);                             // 25,165,824
    float*  qb   = (float*)(ws + 25165824);                   //  1,048,576
    float*  kb   = (float*)(ws + 26214400);                   //  1,048,576
    float*  vb   = (float*)(ws + 27262976);                   //  1,048,576
    float*  yb   = (float*)(ws + 28311552);                   //  1,048,576  -> ~29.4 MB
    float*  x    = (float*)d_out;

    k_geo<<<dim3(2048), dim3(256), 0, stream>>>(boxes, Wg, bg, dv, mask, lg);

    for (int l = 0; l < LLn; ++l) {
        const float* Wq_l = Wq + (size_t)l * DDm * DDm;
        const float* Wk_l = Wk + (size_t)l * DDm * DDm;
        const float* Wv_l = Wv + (size_t)l * DDm * DDm;
        const float* Wo_l = Wo + (size_t)l * DDm * DDm;
        const float* bq_l = bq + (size_t)l * DDm;
        const float* bk_l = bk + (size_t)l * DDm;
        const float* bv_l = bv + (size_t)l * DDm;
        const float* bo_l = bo + (size_t)l * DDm;
        const float* xin  = (l == 0) ? features : x;   // layer-0 reads features directly

        k_gemm_mfma<<<dim3(32, 4, 3), dim3(256), 0, stream>>>(
            xin, Wq_l, Wk_l, Wv_l, bq_l, bk_l, bv_l, qb, kb, vb, nullptr);
        k_attn<<<dim3(32, 16), dim3(256), 0, stream>>>(qb, kb, vb, lg, yb, l);
        k_gemm_mfma<<<dim3(32, 4, 1), dim3(256), 0, stream>>>(
            yb, Wo_l, Wo_l, Wo_l, bo_l, bo_l, bo_l, x, x, x, xin);
    }
}

// Round 12
// 118.583 us; speedup vs baseline: 2.1386x; 1.3290x over previous
//
#include <hip/hip_runtime.h>
#include <hip/hip_fp16.h>

// Problem constants (from reference): B=2, N=512, D=256, H=8, L=3
#define BB 2
#define NNq 512
#define DDm 256
#define HHh 8
#define DHh 32
#define LLn 3

static constexpr float EPSF   = 1e-4f;
static constexpr float INV2PI = 0.15915494309189535f;   // 1/(2*pi)
static constexpr float SCALE  = 0.17677669529663687f;   // 1/sqrt(32)

#if __has_builtin(__builtin_amdgcn_fractf)
#define FRACTF(x) __builtin_amdgcn_fractf(x)
#else
#define FRACTF(x) ((x) - floorf(x))
#endif
#if __has_builtin(__builtin_amdgcn_sinf)
#define SINR(x) __builtin_amdgcn_sinf(x)   // sin(2*pi*x), x in revolutions
#define COSR(x) __builtin_amdgcn_cosf(x)
#else
#define SINR(x) __sinf((x) * 6.2831853071795865f)
#define COSR(x) __cosf((x) * 6.2831853071795865f)
#endif

typedef _Float16 f16x8 __attribute__((ext_vector_type(8)));
typedef _Float16 f16x4 __attribute__((ext_vector_type(4)));
typedef _Float16 f16x2 __attribute__((ext_vector_type(2)));
typedef float    f32x4 __attribute__((ext_vector_type(4)));

__device__ inline f16x2 pk2(float a, float b) {
#if __has_builtin(__builtin_amdgcn_cvt_pkrtz)
    return __builtin_bit_cast(f16x2, __builtin_amdgcn_cvt_pkrtz(a, b));
#else
    f16x2 r; r[0] = (_Float16)a; r[1] = (_Float16)b; return r;
#endif
}
union U16x8 { f16x8 v; f16x2 h[4]; };

// ---------------------------------------------------------------- weight pre-convert
// W[l][k][n] fp32 -> WT[(l*4+op)][n][k] fp16, LDS-bounce transpose (coalesced
// both sides; avoids 2B-scatter RMW). Runs once, 192 blocks.
__global__ __launch_bounds__(256) void k_wcvt(const float* __restrict__ Wq,
        const float* __restrict__ Wk, const float* __restrict__ Wv,
        const float* __restrict__ Wo, _Float16* __restrict__ WT) {
    __shared__ _Float16 t[64][72];   // pad 72 halfs = 144B (16B-aligned rows)
    const int tid = threadIdx.x;
    const int mat = blockIdx.z;              // l*4 + op
    const int l = mat >> 2, op = mat & 3;
    const float* W = (op == 0 ? Wq : op == 1 ? Wk : op == 2 ? Wv : Wo)
                     + (size_t)l * 65536;
    const int k0 = blockIdx.x * 64, n0 = blockIdx.y * 64;
    for (int u = tid; u < 64 * 16; u += 256) {       // read [64k][64n], cvt, transpose
        int k = u >> 4, n4 = (u & 15) * 4;
        float4 w4 = *reinterpret_cast<const float4*>(&W[(size_t)(k0 + k) * 256 + n0 + n4]);
        t[n4 + 0][k] = (_Float16)w4.x; t[n4 + 1][k] = (_Float16)w4.y;
        t[n4 + 2][k] = (_Float16)w4.z; t[n4 + 3][k] = (_Float16)w4.w;
    }
    __syncthreads();
    for (int u = tid; u < 64 * 8; u += 256) {        // write rows of WT coalesced
        int n = u >> 3, kc = (u & 7) * 8;
        *reinterpret_cast<f16x8*>(&WT[((size_t)mat * 256 + n0 + n) * 256 + k0 + kc]) =
            *reinterpret_cast<const f16x8*>(&t[n][kc]);
    }
}

// ---------------------------------------------------------------- geo (MFMA, fp16)
// Round-9 plateau structure (49-55us across 3 structural variants; trans/issue
// bound). boxprep folded inline; log+mask folded into write-out.
__global__ __launch_bounds__(256) void k_geo(const float* __restrict__ boxes,
                                             const float* __restrict__ Wg,
                                             const float* __restrict__ bg,
                                             const float* __restrict__ divm,
                                             const int* __restrict__ maskp,
                                             __half* __restrict__ lg) {
    __shared__ char smem[16384];     // union: WgT (16384B) then obuf (13056B)
    _Float16* WgT = reinterpret_cast<_Float16*>(smem);          // [32][256]
    __half (*obuf)[24][68] = reinterpret_cast<__half (*)[24][68]>(smem);

    const int tid = threadIdx.x;
    for (int idx = tid; idx < 32 * 256; idx += 256) {
        int n = idx >> 8, k = idx & 255;
        float w = (n < 24) ? Wg[(size_t)(n >> 3) * 2048 + (size_t)k * 8 + (n & 7)] : 0.f;
        WgT[n * 256 + (k ^ ((n & 7) << 3))] = (_Float16)w;
    }
    __syncthreads();

    const int lane = tid & 63;
    const int wid  = tid >> 6;
    const int ln15 = lane & 15;
    const int kgrp = lane >> 4;          // 0..3

    float invd[8];
    {
        const float4* dv4 = reinterpret_cast<const float4*>(divm);
        float4 da = dv4[kgrp * 2], db = dv4[kgrp * 2 + 1];
        invd[0] = INV2PI / da.x; invd[1] = INV2PI / da.y;
        invd[2] = INV2PI / da.z; invd[3] = INV2PI / da.w;
        invd[4] = INV2PI / db.x; invd[5] = INV2PI / db.y;
        invd[6] = INV2PI / db.z; invd[7] = INV2PI / db.w;
    }
    const int n0 = ln15;
    const int n1 = 16 + ln15;
    const float bg0 = bg[n0];
    const float bg1 = (n1 < 24) ? bg[n1] : 0.f;

    const int mask  = (ln15 & 7) << 3;
    const int flip5 = mask & 32;
    const int kb    = (kgrp << 3) ^ (mask & 24);
    const int base0 = n0 * 256 + kb;
    const int base1 = n1 * 256 + kb;

    f16x8 bS0[4], bC0[4], bS1[4], bC1[4];
#pragma unroll
    for (int kc2 = 0; kc2 < 4; ++kc2) {
        const int koffS = ((2 * kc2) * 32) ^ flip5;
        const int koffC = ((2 * kc2 + 1) * 32) ^ flip5;
        bS0[kc2] = *reinterpret_cast<const f16x8*>(&WgT[base0 + koffS]);
        bC0[kc2] = *reinterpret_cast<const f16x8*>(&WgT[base0 + koffC]);
        bS1[kc2] = *reinterpret_cast<const f16x8*>(&WgT[base1 + koffS]);
        bC1[kc2] = *reinterpret_cast<const f16x8*>(&WgT[base1 + koffC]);
    }
    __syncthreads();   // ALL waves done reading WgT before obuf overwrites it

    const float4* boxes4 = reinterpret_cast<const float4*>(boxes);
    const size_t plane = (size_t)NNq * NNq;

    const int base4 = (blockIdx.x * 4 + wid) * 4;
#pragma unroll
    for (int it = 0; it < 4; ++it) {
        const int slab = base4 + it;
        const int p0 = slab << 4;
        const int b  = p0 >> 18;
        const int rem = p0 & (NNq * NNq - 1);
        const int i  = rem >> 9;
        const int j0 = rem & (NNq - 1);

        float4 Bi = boxes4[b * NNq + i];
        float4 Bj = boxes4[b * NNq + j0 + ln15];
        float cxi = 0.5f * (Bi.x + Bi.z), cyi = 0.5f * (Bi.y + Bi.w);
        float wi  = fmaxf(Bi.z - Bi.x, EPSF), hi = fmaxf(Bi.w - Bi.y, EPSF);
        float cxj = 0.5f * (Bj.x + Bj.z), cyj = 0.5f * (Bj.y + Bj.w);
        float wj  = fmaxf(Bj.z - Bj.x, EPSF), hj = fmaxf(Bj.w - Bj.y, EPSF);
        float rel[4];
        rel[0] = __logf(fabsf(cxj - cxi) / wj + EPSF);
        rel[1] = __logf(fabsf(cyj - cyi) / hj + EPSF);
        rel[2] = __logf(wi / wj + EPSF);
        rel[3] = __logf(hi / hj + EPSF);

        f32x4 acc0 = {0.f, 0.f, 0.f, 0.f};
        f32x4 acc1 = {0.f, 0.f, 0.f, 0.f};

#pragma unroll
        for (int kc2 = 0; kc2 < 4; ++kc2) {
            const float rc = rel[kc2];
            U16x8 afs, afc;
#pragma unroll
            for (int jj = 0; jj < 4; ++jj) {
                float rv0 = FRACTF(rc * invd[2 * jj]);
                float rv1 = FRACTF(rc * invd[2 * jj + 1]);
                afs.h[jj] = pk2(SINR(rv0), SINR(rv1));
                afc.h[jj] = pk2(COSR(rv0), COSR(rv1));
            }
            acc0 = __builtin_amdgcn_mfma_f32_16x16x32_f16(afs.v, bS0[kc2], acc0, 0, 0, 0);
            acc0 = __builtin_amdgcn_mfma_f32_16x16x32_f16(afc.v, bC0[kc2], acc0, 0, 0, 0);
            acc1 = __builtin_amdgcn_mfma_f32_16x16x32_f16(afs.v, bS1[kc2], acc1, 0, 0, 0);
            acc1 = __builtin_amdgcn_mfma_f32_16x16x32_f16(afc.v, bC1[kc2], acc1, 0, 0, 0);
        }

#pragma unroll
        for (int r = 0; r < 4; ++r) {
            const int m = it * 16 + (kgrp << 2) + r;
            float g0 = fmaxf(acc0[r] + bg0, 0.f);
            obuf[wid][n0][m] = __float2half(g0);
            if (n1 < 24) {
                float g1 = fmaxf(acc1[r] + bg1, 0.f);
                obuf[wid][n1][m] = __float2half(g1);
            }
        }
    }
    __syncthreads();

    const int b_  = base4 >> 14;
    const int i_  = (base4 >> 5) & (NNq - 1);
    const int j0b = (base4 & 31) << 4;
    const int mv  = maskp[((size_t)b_ * NNq + i_) * NNq + j0b + lane];
    size_t obase = (size_t)b_ * plane + (size_t)i_ * NNq + j0b + lane;
#pragma unroll
    for (int t = 0; t < 24; ++t) {
        float g = __half2float(obuf[wid][t][lane]);
        float v = (mv != 0) ? __logf(g + 1e-6f) : -60000.0f;
        lg[obase + (size_t)t * (BB * plane)] = __float2half(v);
    }
}

// ---------------------------------------------------------------- GEMM qkv (A fp32 -> C fp16)
// tile 32(M) x 64(N); weights from pre-transposed fp16 WT (pure 16B copies).
#define LDP 264
__global__ __launch_bounds__(256) void k_gemm_qkv(const float* __restrict__ A,
        const _Float16* __restrict__ WT0, const _Float16* __restrict__ WT1,
        const _Float16* __restrict__ WT2,
        const float* __restrict__ b0, const float* __restrict__ b1, const float* __restrict__ b2,
        _Float16* __restrict__ C0, _Float16* __restrict__ C1, _Float16* __restrict__ C2) {
    const _Float16* WTz = (blockIdx.z == 0) ? WT0 : (blockIdx.z == 1) ? WT1 : WT2;
    const float*    bia = (blockIdx.z == 0) ? b0 : (blockIdx.z == 1) ? b1 : b2;
    _Float16*       C   = (blockIdx.z == 0) ? C0 : (blockIdx.z == 1) ? C1 : C2;

    __shared__ _Float16 As[32 * LDP];
    __shared__ _Float16 Ws[64 * LDP];

    const int tid = threadIdx.x;
    const int m0 = blockIdx.x * 32, n0 = blockIdx.y * 64;

    for (int u = tid; u < 32 * 64; u += 256) {          // A fp32 -> fp16
        int m = u >> 6, k4 = (u & 63) * 4;
        float4 av = *reinterpret_cast<const float4*>(&A[(size_t)(m0 + m) * 256 + k4]);
        f16x4 hv = {(_Float16)av.x, (_Float16)av.y, (_Float16)av.z, (_Float16)av.w};
        *reinterpret_cast<f16x4*>(&As[m * LDP + k4]) = hv;
    }
    for (int u = tid; u < 2048; u += 256) {             // W: straight 16B copies
        int n = u >> 5, kc = (u & 31) * 8;
        *reinterpret_cast<f16x8*>(&Ws[n * LDP + kc]) =
            *reinterpret_cast<const f16x8*>(&WTz[(size_t)(n0 + n) * 256 + kc]);
    }
    __syncthreads();

    const int lane = tid & 63;
    const int wid  = tid >> 6;
    const int ln15 = lane & 15;
    const int kgrp = lane >> 4;
    const int mw   = (wid & 1) * 16;
    const int nsel = (wid >> 1) * 16;
    const int kfr  = kgrp * 8;

    f32x4 acc[2] = {{0.f,0.f,0.f,0.f},{0.f,0.f,0.f,0.f}};
#pragma unroll
    for (int kc = 0; kc < 8; ++kc) {
        f16x8 af = *reinterpret_cast<const f16x8*>(&As[(mw + ln15) * LDP + kc * 32 + kfr]);
#pragma unroll
        for (int t = 0; t < 2; ++t) {
            f16x8 bf = *reinterpret_cast<const f16x8*>(
                &Ws[(nsel + t * 32 + ln15) * LDP + kc * 32 + kfr]);
            acc[t] = __builtin_amdgcn_mfma_f32_16x16x32_f16(af, bf, acc[t], 0, 0, 0);
        }
    }

#pragma unroll
    for (int t = 0; t < 2; ++t) {
        const int col = n0 + nsel + t * 32 + ln15;
        const float bv = bia[col];
#pragma unroll
        for (int r = 0; r < 4; ++r) {
            const int row = m0 + mw + kgrp * 4 + r;
            C[(size_t)row * 256 + col] = (_Float16)fmaxf(acc[t][r] + bv, 0.f);
        }
    }
}

// ---------------------------------------------------------------- GEMM o (A fp16 -> C fp32 + resid)
__global__ __launch_bounds__(256) void k_gemm_o(const _Float16* __restrict__ A,
        const _Float16* __restrict__ WT0,
        const float* __restrict__ bia,
        float* __restrict__ C, const float* __restrict__ resid) {
    __shared__ _Float16 As[32 * LDP];
    __shared__ _Float16 Ws[64 * LDP];

    const int tid = threadIdx.x;
    const int m0 = blockIdx.x * 32, n0 = blockIdx.y * 64;

    for (int u = tid; u < 1024; u += 256) {             // A: straight 16B copies
        int m = u >> 5, kc = (u & 31) * 8;
        *reinterpret_cast<f16x8*>(&As[m * LDP + kc]) =
            *reinterpret_cast<const f16x8*>(&A[(size_t)(m0 + m) * 256 + kc]);
    }
    for (int u = tid; u < 2048; u += 256) {             // W: straight 16B copies
        int n = u >> 5, kc = (u & 31) * 8;
        *reinterpret_cast<f16x8*>(&Ws[n * LDP + kc]) =
            *reinterpret_cast<const f16x8*>(&WT0[(size_t)(n0 + n) * 256 + kc]);
    }
    __syncthreads();

    const int lane = tid & 63;
    const int wid  = tid >> 6;
    const int ln15 = lane & 15;
    const int kgrp = lane >> 4;
    const int mw   = (wid & 1) * 16;
    const int nsel = (wid >> 1) * 16;
    const int kfr  = kgrp * 8;

    f32x4 acc[2] = {{0.f,0.f,0.f,0.f},{0.f,0.f,0.f,0.f}};
#pragma unroll
    for (int kc = 0; kc < 8; ++kc) {
        f16x8 af = *reinterpret_cast<const f16x8*>(&As[(mw + ln15) * LDP + kc * 32 + kfr]);
#pragma unroll
        for (int t = 0; t < 2; ++t) {
            f16x8 bf = *reinterpret_cast<const f16x8*>(
                &Ws[(nsel + t * 32 + ln15) * LDP + kc * 32 + kfr]);
            acc[t] = __builtin_amdgcn_mfma_f32_16x16x32_f16(af, bf, acc[t], 0, 0, 0);
        }
    }

#pragma unroll
    for (int t = 0; t < 2; ++t) {
        const int col = n0 + nsel + t * 32 + ln15;
        const float bv = bia[col];
#pragma unroll
        for (int r = 0; r < 4; ++r) {
            const int row = m0 + mw + kgrp * 4 + r;
            float o = fmaxf(acc[t][r] + bv, 0.f) + resid[(size_t)row * 256 + col];
            C[(size_t)row * 256 + col] = o;
        }
    }
}

// ---------------------------------------------------------------- fused attention (MFMA v2, fp16 I/O)
// Round-11 verified structure; q/k/v now fp16 in global (staging = straight
// copies, Q-frag = one 16B load), y written fp16.
__global__ __launch_bounds__(256) void k_attn(const _Float16* __restrict__ q,
                                              const _Float16* __restrict__ kk,
                                              const _Float16* __restrict__ vv,
                                              const __half* __restrict__ lg,
                                              _Float16* __restrict__ y, int l) {
    __shared__ _Float16 Kh[512 * 32];   // 32 KB, row j: 64B, swz ((j&7)<<4)
    __shared__ _Float16 VT[32 * 512];   // 32 KB, row d: 1KB, swz ((d&7)<<4)
    __shared__ _Float16 Ps[4][16 * 128];// 16 KB, per-wave, swz ((i&7)<<4)

    const int bh = blockIdx.y;
    const int b = bh >> 3, h = bh & 7;
    const int i0t = blockIdx.x * 16;

    const int tid  = threadIdx.x;
    const int lane = tid & 63, wid = tid >> 6;
    const int ln15 = lane & 15, kgrp = lane >> 4;

    // stage K and V (fp16 straight copies; V transposed)
    for (int u = tid; u < 2048; u += 256) {
        int j = u >> 2, d8 = (u & 3) * 8;
        const size_t src = (size_t)(b * NNq + j) * DDm + h * DHh + d8;
        f16x8 kv = *reinterpret_cast<const f16x8*>(&kk[src]);
        *reinterpret_cast<f16x8*>(reinterpret_cast<char*>(Kh) +
            ((j * 64 + d8 * 2) ^ ((j & 7) << 4))) = kv;
        f16x8 v8 = *reinterpret_cast<const f16x8*>(&vv[src]);
#pragma unroll
        for (int e = 0; e < 8; ++e) {
            int row = d8 + e;
            *reinterpret_cast<_Float16*>(reinterpret_cast<char*>(VT) +
                ((row * 1024 + j * 2) ^ ((row & 7) << 4))) = v8[e];
        }
    }

    // Q-fragment: one 16B load
    f16x8 qf = *reinterpret_cast<const f16x8*>(
        &q[(size_t)(b * NNq + i0t + ln15) * DDm + h * DHh + kgrp * 8]);
    __syncthreads();

    const int jbase = wid * 128;
    const size_t plane = (size_t)NNq * NNq;
    const size_t lg_base = (size_t)((l * 8 + h) * BB + b) * plane;

    // QK^T: 8 MFMAs -> lane holds S[i=kgrp*4+r][j=jbase+t*16+ln15]
    f32x4 s[8];
#pragma unroll
    for (int t = 0; t < 8; ++t) {
        int j = jbase + t * 16 + ln15;
        f16x8 kf = *reinterpret_cast<const f16x8*>(reinterpret_cast<char*>(Kh) +
            ((j * 64 + kgrp * 16) ^ ((j & 7) << 4)));
        f32x4 z = {0.f, 0.f, 0.f, 0.f};
        s[t] = __builtin_amdgcn_mfma_f32_16x16x32_f16(qf, kf, z, 0, 0, 0);
    }

    // scale + lg (log(geo)+mask prefolded)
#pragma unroll
    for (int t = 0; t < 8; ++t) {
        const size_t jg = jbase + t * 16 + ln15;
#pragma unroll
        for (int r = 0; r < 4; ++r) {
            float lgv = __half2float(lg[lg_base + (size_t)(i0t + kgrp * 4 + r) * NNq + jg]);
            s[t][r] = s[t][r] * SCALE + lgv;
        }
    }

    // one-shot softmax over the wave's 128-j slice
    float m_[4], l_[4];
#pragma unroll
    for (int r = 0; r < 4; ++r) {
        float mx = s[0][r];
#pragma unroll
        for (int t = 1; t < 8; ++t) mx = fmaxf(mx, s[t][r]);
#pragma unroll
        for (int o = 1; o < 16; o <<= 1) mx = fmaxf(mx, __shfl_xor(mx, o, 64));
        float sum = 0.f;
#pragma unroll
        for (int t = 0; t < 8; ++t) {
            float p = __expf(s[t][r] - mx);
            s[t][r] = p; sum += p;
        }
#pragma unroll
        for (int o = 1; o < 16; o <<= 1) sum += __shfl_xor(sum, o, 64);
        m_[r] = mx; l_[r] = sum;
    }

    // P -> wave-private LDS (fp16, swizzled); no barrier needed
    {
        char* psb = reinterpret_cast<char*>(Ps[wid]);
#pragma unroll
        for (int r = 0; r < 4; ++r) {
            const int row = kgrp * 4 + r;
            const int rb = row * 256, sw = (row & 7) << 4;
#pragma unroll
            for (int t = 0; t < 8; ++t) {
                int byte = (rb + (t * 16 + ln15) * 2) ^ sw;
                *reinterpret_cast<_Float16*>(psb + byte) = (_Float16)s[t][r];
            }
        }
    }

    // PV: 4 j-chunks x 2 d-tiles
    f32x4 oacc[2] = {{0.f,0.f,0.f,0.f},{0.f,0.f,0.f,0.f}};
    {
        char* psb = reinterpret_cast<char*>(Ps[wid]);
#pragma unroll
        for (int kc = 0; kc < 4; ++kc) {
            f16x8 pf = *reinterpret_cast<const f16x8*>(psb +
                ((ln15 * 256 + kc * 64 + kgrp * 16) ^ ((ln15 & 7) << 4)));
#pragma unroll
            for (int dt = 0; dt < 2; ++dt) {
                int d = dt * 16 + ln15;
                f16x8 vf = *reinterpret_cast<const f16x8*>(reinterpret_cast<char*>(VT) +
                    ((d * 1024 + (jbase + kc * 32 + kgrp * 8) * 2) ^ ((d & 7) << 4)));
                oacc[dt] = __builtin_amdgcn_mfma_f32_16x16x32_f16(pf, vf, oacc[dt], 0, 0, 0);
            }
        }
    }

    // write partials into this wave's (dead) K slab: [16][32] O + m[16] + l[16]
    {
        float* Op = reinterpret_cast<float*>(reinterpret_cast<char*>(Kh) + wid * 8192);
#pragma unroll
        for (int dt = 0; dt < 2; ++dt)
#pragma unroll
            for (int r = 0; r < 4; ++r)
                Op[(kgrp * 4 + r) * 32 + dt * 16 + ln15] = oacc[dt][r];
        if (ln15 == 0) {
#pragma unroll
            for (int r = 0; r < 4; ++r) {
                Op[512 + kgrp * 4 + r] = m_[r];
                Op[528 + kgrp * 4 + r] = l_[r];
            }
        }
    }
    __syncthreads();

    // flash-combine across 4 waves; thread -> (i = tid>>4, d0 = (tid&15)*2)
    {
        const int i = tid >> 4, d0 = (tid & 15) * 2;
        float mw[4], M = -3.0e38f;
#pragma unroll
        for (int w = 0; w < 4; ++w) {
            mw[w] = reinterpret_cast<float*>(reinterpret_cast<char*>(Kh) + w * 8192)[512 + i];
            M = fmaxf(M, mw[w]);
        }
        float o0 = 0.f, o1 = 0.f, ls = 0.f;
#pragma unroll
        for (int w = 0; w < 4; ++w) {
            float* Op = reinterpret_cast<float*>(reinterpret_cast<char*>(Kh) + w * 8192);
            float sc = __expf(mw[w] - M);
            ls += Op[528 + i] * sc;
            o0 += Op[i * 32 + d0] * sc;
            o1 += Op[i * 32 + d0 + 1] * sc;
        }
        float inv = 1.0f / ls;
        f16x2 ov; ov[0] = (_Float16)(o0 * inv); ov[1] = (_Float16)(o1 * inv);
        *reinterpret_cast<f16x2*>(&y[(size_t)(b * NNq + i0t + i) * DDm + h * DHh + d0]) = ov;
    }
}

// ---------------------------------------------------------------- launch
extern "C" void kernel_launch(void* const* d_in, const int* in_sizes, int n_in,
                              void* d_out, int out_size, void* d_ws, size_t ws_size,
                              hipStream_t stream) {
    const float* boxes    = (const float*)d_in[0];
    const float* features = (const float*)d_in[1];
    const int*   mask     = (const int*)d_in[2];
    const float* Wq = (const float*)d_in[3];
    const float* bq = (const float*)d_in[4];
    const float* Wk = (const float*)d_in[5];
    const float* bk = (const float*)d_in[6];
    const float* Wv = (const float*)d_in[7];
    const float* bv = (const float*)d_in[8];
    const float* Wo = (const float*)d_in[9];
    const float* bo = (const float*)d_in[10];
    const float* Wg = (const float*)d_in[11];
    const float* bg = (const float*)d_in[12];
    const float* dv = (const float*)d_in[13];

    char* ws = (char*)d_ws;
    __half*    lg = (__half*)(ws);                         // 25,165,824
    _Float16*  WT = (_Float16*)(ws + 25165824);            //  1,572,864 (12 x 256 x 256 fp16)
    _Float16*  qb = (_Float16*)(ws + 26738688);            //    524,288
    _Float16*  kb = (_Float16*)(ws + 27262976);            //    524,288
    _Float16*  vb = (_Float16*)(ws + 27787264);            //    524,288
    _Float16*  yb = (_Float16*)(ws + 28311552);            //    524,288  -> ~28.8 MB
    float*     x  = (float*)d_out;

    k_wcvt<<<dim3(4, 4, 12), dim3(256), 0, stream>>>(Wq, Wk, Wv, Wo, WT);
    k_geo<<<dim3(2048), dim3(256), 0, stream>>>(boxes, Wg, bg, dv, mask, lg);

    for (int l = 0; l < LLn; ++l) {
        const _Float16* WTq = WT + (size_t)(l * 4 + 0) * 65536;
        const _Float16* WTk = WT + (size_t)(l * 4 + 1) * 65536;
        const _Float16* WTv = WT + (size_t)(l * 4 + 2) * 65536;
        const _Float16* WTo = WT + (size_t)(l * 4 + 3) * 65536;
        const float* bq_l = bq + (size_t)l * DDm;
        const float* bk_l = bk + (size_t)l * DDm;
        const float* bv_l = bv + (size_t)l * DDm;
        const float* bo_l = bo + (size_t)l * DDm;
        const float* xin  = (l == 0) ? features : x;   // layer-0 reads features directly

        k_gemm_qkv<<<dim3(32, 4, 3), dim3(256), 0, stream>>>(
            xin, WTq, WTk, WTv, bq_l, bk_l, bv_l, qb, kb, vb);
        k_attn<<<dim3(32, 16), dim3(256), 0, stream>>>(qb, kb, vb, lg, yb, l);
        k_gemm_o<<<dim3(32, 4), dim3(256), 0, stream>>>(
            yb, WTo, bo_l, x, xin);
    }
}

// Round 13
// 101.285 us; speedup vs baseline: 2.5038x; 1.1708x over previous
//
#include <hip/hip_runtime.h>
#include <hip/hip_fp16.h>

// Problem constants (from reference): B=2, N=512, D=256, H=8, L=3
#define BB 2
#define NNq 512
#define DDm 256
#define HHh 8
#define DHh 32
#define LLn 3

static constexpr float EPSF   = 1e-4f;
static constexpr float INV2PI = 0.15915494309189535f;   // 1/(2*pi)
static constexpr float SCALE  = 0.17677669529663687f;   // 1/sqrt(32)

#if __has_builtin(__builtin_amdgcn_fractf)
#define FRACTF(x) __builtin_amdgcn_fractf(x)
#else
#define FRACTF(x) ((x) - floorf(x))
#endif
#if __has_builtin(__builtin_amdgcn_sinf)
#define SINR(x) __builtin_amdgcn_sinf(x)   // sin(2*pi*x), x in revolutions
#define COSR(x) __builtin_amdgcn_cosf(x)
#else
#define SINR(x) __sinf((x) * 6.2831853071795865f)
#define COSR(x) __cosf((x) * 6.2831853071795865f)
#endif

typedef _Float16 f16x8 __attribute__((ext_vector_type(8)));
typedef _Float16 f16x4 __attribute__((ext_vector_type(4)));
typedef _Float16 f16x2 __attribute__((ext_vector_type(2)));
typedef float    f32x4 __attribute__((ext_vector_type(4)));

__device__ inline f16x2 pk2(float a, float b) {
#if __has_builtin(__builtin_amdgcn_cvt_pkrtz)
    return __builtin_bit_cast(f16x2, __builtin_amdgcn_cvt_pkrtz(a, b));
#else
    f16x2 r; r[0] = (_Float16)a; r[1] = (_Float16)b; return r;
#endif
}
union U16x8 { f16x8 v; f16x2 h[4]; };

// ---------------------------------------------------------------- weight pre-convert
// z<12: W[l][k][n] fp32 -> WT[(l*4+op)][n][k] fp16 (LDS-bounce transpose).
// z==12 (block 0,0): Wg -> WgTg[32][256] fp16 with the k-XOR swizzle baked,
// so k_geo can load its B-fragments global->register with zero staging.
__global__ __launch_bounds__(256) void k_wcvt(const float* __restrict__ Wq,
        const float* __restrict__ Wk, const float* __restrict__ Wv,
        const float* __restrict__ Wo, _Float16* __restrict__ WT,
        const float* __restrict__ Wg, _Float16* __restrict__ WgTg) {
    __shared__ _Float16 t[64][72];
    const int tid = threadIdx.x;
    const int mat = blockIdx.z;
    if (mat == 12) {
        if (blockIdx.x == 0 && blockIdx.y == 0) {
            for (int idx = tid; idx < 32 * 256; idx += 256) {
                int n = idx >> 8, k = idx & 255;
                float w = (n < 24) ? Wg[(size_t)(n >> 3) * 2048 + (size_t)k * 8 + (n & 7)] : 0.f;
                WgTg[n * 256 + (k ^ ((n & 7) << 3))] = (_Float16)w;
            }
        }
        return;
    }
    const int l = mat >> 2, op = mat & 3;
    const float* W = (op == 0 ? Wq : op == 1 ? Wk : op == 2 ? Wv : Wo)
                     + (size_t)l * 65536;
    const int k0 = blockIdx.x * 64, n0 = blockIdx.y * 64;
    for (int u = tid; u < 64 * 16; u += 256) {
        int k = u >> 4, n4 = (u & 15) * 4;
        float4 w4 = *reinterpret_cast<const float4*>(&W[(size_t)(k0 + k) * 256 + n0 + n4]);
        t[n4 + 0][k] = (_Float16)w4.x; t[n4 + 1][k] = (_Float16)w4.y;
        t[n4 + 2][k] = (_Float16)w4.z; t[n4 + 3][k] = (_Float16)w4.w;
    }
    __syncthreads();
    for (int u = tid; u < 64 * 8; u += 256) {
        int n = u >> 3, kc = (u & 7) * 8;
        *reinterpret_cast<f16x8*>(&WT[((size_t)mat * 256 + n0 + n) * 256 + k0 + kc]) =
            *reinterpret_cast<const f16x8*>(&t[n][kc]);
    }
}

// ---------------------------------------------------------------- geo (MFMA, fp16)
// Round-13: B-fragments loaded global->register from pre-swizzled WgTg (16KB,
// L1-hot) -- removes the 8x-strided per-block LDS staging (~400MB inflated L2
// traffic) and its barrier. launch_bounds(256,4) = 128 VGPR budget so the 16
// f16x8 fragments actually stay register-resident (round-12 VGPR=60 proved
// they didn't). Output is now G = mask ? relu(emb@Wg+bg)+1e-6 : 0 (NO log) --
// attention uses p = G*exp(qk*SCALE-m), mathematically identical softmax.
__global__ __launch_bounds__(256, 4) void k_geo(const float* __restrict__ boxes,
                                                const _Float16* __restrict__ WgTg,
                                                const float* __restrict__ bg,
                                                const float* __restrict__ divm,
                                                const int* __restrict__ maskp,
                                                __half* __restrict__ G) {
    __shared__ __half obuf[4][24][68];   // 13 KB

    const int tid  = threadIdx.x;
    const int lane = tid & 63;
    const int wid  = tid >> 6;
    const int ln15 = lane & 15;
    const int kgrp = lane >> 4;

    float invd[8];
    {
        const float4* dv4 = reinterpret_cast<const float4*>(divm);
        float4 da = dv4[kgrp * 2], db = dv4[kgrp * 2 + 1];
        invd[0] = INV2PI / da.x; invd[1] = INV2PI / da.y;
        invd[2] = INV2PI / da.z; invd[3] = INV2PI / da.w;
        invd[4] = INV2PI / db.x; invd[5] = INV2PI / db.y;
        invd[6] = INV2PI / db.z; invd[7] = INV2PI / db.w;
    }
    const int n0 = ln15;
    const int n1 = 16 + ln15;
    const float bg0 = bg[n0];
    const float bg1 = (n1 < 24) ? bg[n1] : 0.f;

    const int mask  = (ln15 & 7) << 3;
    const int flip5 = mask & 32;
    const int kb    = (kgrp << 3) ^ (mask & 24);
    const int base0 = n0 * 256 + kb;
    const int base1 = n1 * 256 + kb;

    // loop-invariant B-fragments: 16 x 16B global loads (L1/L2-hot table)
    f16x8 bS0[4], bC0[4], bS1[4], bC1[4];
#pragma unroll
    for (int kc2 = 0; kc2 < 4; ++kc2) {
        const int koffS = ((2 * kc2) * 32) ^ flip5;
        const int koffC = ((2 * kc2 + 1) * 32) ^ flip5;
        bS0[kc2] = *reinterpret_cast<const f16x8*>(&WgTg[base0 + koffS]);
        bC0[kc2] = *reinterpret_cast<const f16x8*>(&WgTg[base0 + koffC]);
        bS1[kc2] = *reinterpret_cast<const f16x8*>(&WgTg[base1 + koffS]);
        bC1[kc2] = *reinterpret_cast<const f16x8*>(&WgTg[base1 + koffC]);
    }

    const float4* boxes4 = reinterpret_cast<const float4*>(boxes);
    const size_t plane = (size_t)NNq * NNq;

    const int base4 = (blockIdx.x * 4 + wid) * 4;
#pragma unroll
    for (int it = 0; it < 4; ++it) {
        const int slab = base4 + it;
        const int p0 = slab << 4;
        const int b  = p0 >> 18;
        const int rem = p0 & (NNq * NNq - 1);
        const int i  = rem >> 9;
        const int j0 = rem & (NNq - 1);

        float4 Bi = boxes4[b * NNq + i];
        float4 Bj = boxes4[b * NNq + j0 + ln15];
        float cxi = 0.5f * (Bi.x + Bi.z), cyi = 0.5f * (Bi.y + Bi.w);
        float wi  = fmaxf(Bi.z - Bi.x, EPSF), hi = fmaxf(Bi.w - Bi.y, EPSF);
        float cxj = 0.5f * (Bj.x + Bj.z), cyj = 0.5f * (Bj.y + Bj.w);
        float wj  = fmaxf(Bj.z - Bj.x, EPSF), hj = fmaxf(Bj.w - Bj.y, EPSF);
        float rel[4];
        rel[0] = __logf(fabsf(cxj - cxi) / wj + EPSF);
        rel[1] = __logf(fabsf(cyj - cyi) / hj + EPSF);
        rel[2] = __logf(wi / wj + EPSF);
        rel[3] = __logf(hi / hj + EPSF);

        f32x4 acc0 = {0.f, 0.f, 0.f, 0.f};
        f32x4 acc1 = {0.f, 0.f, 0.f, 0.f};

#pragma unroll
        for (int kc2 = 0; kc2 < 4; ++kc2) {
            const float rc = rel[kc2];
            U16x8 afs, afc;
#pragma unroll
            for (int jj = 0; jj < 4; ++jj) {
                float rv0 = FRACTF(rc * invd[2 * jj]);
                float rv1 = FRACTF(rc * invd[2 * jj + 1]);
                afs.h[jj] = pk2(SINR(rv0), SINR(rv1));
                afc.h[jj] = pk2(COSR(rv0), COSR(rv1));
            }
            acc0 = __builtin_amdgcn_mfma_f32_16x16x32_f16(afs.v, bS0[kc2], acc0, 0, 0, 0);
            acc0 = __builtin_amdgcn_mfma_f32_16x16x32_f16(afc.v, bC0[kc2], acc0, 0, 0, 0);
            acc1 = __builtin_amdgcn_mfma_f32_16x16x32_f16(afs.v, bS1[kc2], acc1, 0, 0, 0);
            acc1 = __builtin_amdgcn_mfma_f32_16x16x32_f16(afc.v, bC1[kc2], acc1, 0, 0, 0);
        }

#pragma unroll
        for (int r = 0; r < 4; ++r) {
            const int m = it * 16 + (kgrp << 2) + r;
            float g0 = fmaxf(acc0[r] + bg0, 0.f);
            obuf[wid][n0][m] = __float2half(g0);
            if (n1 < 24) {
                float g1 = fmaxf(acc1[r] + bg1, 0.f);
                obuf[wid][n1][m] = __float2half(g1);
            }
        }
    }
    __syncthreads();

    // coalesced write-out: G = mask ? g+1e-6 : 0 (no log)
    const int b_  = base4 >> 14;
    const int i_  = (base4 >> 5) & (NNq - 1);
    const int j0b = (base4 & 31) << 4;
    const int mv  = maskp[((size_t)b_ * NNq + i_) * NNq + j0b + lane];
    size_t obase = (size_t)b_ * plane + (size_t)i_ * NNq + j0b + lane;
#pragma unroll
    for (int t = 0; t < 24; ++t) {
        float g = __half2float(obuf[wid][t][lane]);
        float v = (mv != 0) ? (g + 1e-6f) : 0.0f;
        G[obase + (size_t)t * (BB * plane)] = __float2half(v);
    }
}

// ---------------------------------------------------------------- GEMM qkv (A fp32 -> C fp16)
#define LDP 264
__global__ __launch_bounds__(256) void k_gemm_qkv(const float* __restrict__ A,
        const _Float16* __restrict__ WT0, const _Float16* __restrict__ WT1,
        const _Float16* __restrict__ WT2,
        const float* __restrict__ b0, const float* __restrict__ b1, const float* __restrict__ b2,
        _Float16* __restrict__ C0, _Float16* __restrict__ C1, _Float16* __restrict__ C2) {
    const _Float16* WTz = (blockIdx.z == 0) ? WT0 : (blockIdx.z == 1) ? WT1 : WT2;
    const float*    bia = (blockIdx.z == 0) ? b0 : (blockIdx.z == 1) ? b1 : b2;
    _Float16*       C   = (blockIdx.z == 0) ? C0 : (blockIdx.z == 1) ? C1 : C2;

    __shared__ _Float16 As[32 * LDP];
    __shared__ _Float16 Ws[64 * LDP];

    const int tid = threadIdx.x;
    const int m0 = blockIdx.x * 32, n0 = blockIdx.y * 64;

    for (int u = tid; u < 32 * 64; u += 256) {
        int m = u >> 6, k4 = (u & 63) * 4;
        float4 av = *reinterpret_cast<const float4*>(&A[(size_t)(m0 + m) * 256 + k4]);
        f16x4 hv = {(_Float16)av.x, (_Float16)av.y, (_Float16)av.z, (_Float16)av.w};
        *reinterpret_cast<f16x4*>(&As[m * LDP + k4]) = hv;
    }
    for (int u = tid; u < 2048; u += 256) {
        int n = u >> 5, kc = (u & 31) * 8;
        *reinterpret_cast<f16x8*>(&Ws[n * LDP + kc]) =
            *reinterpret_cast<const f16x8*>(&WTz[(size_t)(n0 + n) * 256 + kc]);
    }
    __syncthreads();

    const int lane = tid & 63;
    const int wid  = tid >> 6;
    const int ln15 = lane & 15;
    const int kgrp = lane >> 4;
    const int mw   = (wid & 1) * 16;
    const int nsel = (wid >> 1) * 16;
    const int kfr  = kgrp * 8;

    f32x4 acc[2] = {{0.f,0.f,0.f,0.f},{0.f,0.f,0.f,0.f}};
#pragma unroll
    for (int kc = 0; kc < 8; ++kc) {
        f16x8 af = *reinterpret_cast<const f16x8*>(&As[(mw + ln15) * LDP + kc * 32 + kfr]);
#pragma unroll
        for (int t = 0; t < 2; ++t) {
            f16x8 bf = *reinterpret_cast<const f16x8*>(
                &Ws[(nsel + t * 32 + ln15) * LDP + kc * 32 + kfr]);
            acc[t] = __builtin_amdgcn_mfma_f32_16x16x32_f16(af, bf, acc[t], 0, 0, 0);
        }
    }

#pragma unroll
    for (int t = 0; t < 2; ++t) {
        const int col = n0 + nsel + t * 32 + ln15;
        const float bv = bia[col];
#pragma unroll
        for (int r = 0; r < 4; ++r) {
            const int row = m0 + mw + kgrp * 4 + r;
            C[(size_t)row * 256 + col] = (_Float16)fmaxf(acc[t][r] + bv, 0.f);
        }
    }
}

// ---------------------------------------------------------------- GEMM o (A fp16 -> C fp32 + resid)
__global__ __launch_bounds__(256) void k_gemm_o(const _Float16* __restrict__ A,
        const _Float16* __restrict__ WT0,
        const float* __restrict__ bia,
        float* __restrict__ C, const float* __restrict__ resid) {
    __shared__ _Float16 As[32 * LDP];
    __shared__ _Float16 Ws[64 * LDP];

    const int tid = threadIdx.x;
    const int m0 = blockIdx.x * 32, n0 = blockIdx.y * 64;

    for (int u = tid; u < 1024; u += 256) {
        int m = u >> 5, kc = (u & 31) * 8;
        *reinterpret_cast<f16x8*>(&As[m * LDP + kc]) =
            *reinterpret_cast<const f16x8*>(&A[(size_t)(m0 + m) * 256 + kc]);
    }
    for (int u = tid; u < 2048; u += 256) {
        int n = u >> 5, kc = (u & 31) * 8;
        *reinterpret_cast<f16x8*>(&Ws[n * LDP + kc]) =
            *reinterpret_cast<const f16x8*>(&WT0[(size_t)(n0 + n) * 256 + kc]);
    }
    __syncthreads();

    const int lane = tid & 63;
    const int wid  = tid >> 6;
    const int ln15 = lane & 15;
    const int kgrp = lane >> 4;
    const int mw   = (wid & 1) * 16;
    const int nsel = (wid >> 1) * 16;
    const int kfr  = kgrp * 8;

    f32x4 acc[2] = {{0.f,0.f,0.f,0.f},{0.f,0.f,0.f,0.f}};
#pragma unroll
    for (int kc = 0; kc < 8; ++kc) {
        f16x8 af = *reinterpret_cast<const f16x8*>(&As[(mw + ln15) * LDP + kc * 32 + kfr]);
#pragma unroll
        for (int t = 0; t < 2; ++t) {
            f16x8 bf = *reinterpret_cast<const f16x8*>(
                &Ws[(nsel + t * 32 + ln15) * LDP + kc * 32 + kfr]);
            acc[t] = __builtin_amdgcn_mfma_f32_16x16x32_f16(af, bf, acc[t], 0, 0, 0);
        }
    }

#pragma unroll
    for (int t = 0; t < 2; ++t) {
        const int col = n0 + nsel + t * 32 + ln15;
        const float bv = bia[col];
#pragma unroll
        for (int r = 0; r < 4; ++r) {
            const int row = m0 + mw + kgrp * 4 + r;
            float o = fmaxf(acc[t][r] + bv, 0.f) + resid[(size_t)row * 256 + col];
            C[(size_t)row * 256 + col] = o;
        }
    }
}

// ---------------------------------------------------------------- fused attention (MFMA v2, multiplicative geo)
// p = G * exp(qk*SCALE - m), m = max(qk*SCALE) over the wave's slice.
// Mathematically identical to softmax(qk*SCALE + log G); G=0 encodes mask.
__global__ __launch_bounds__(256) void k_attn(const _Float16* __restrict__ q,
                                              const _Float16* __restrict__ kk,
                                              const _Float16* __restrict__ vv,
                                              const __half* __restrict__ G,
                                              _Float16* __restrict__ y, int l) {
    __shared__ _Float16 Kh[512 * 32];   // 32 KB, row j: 64B, swz ((j&7)<<4)
    __shared__ _Float16 VT[32 * 512];   // 32 KB, row d: 1KB, swz ((d&7)<<4)
    __shared__ _Float16 Ps[4][16 * 128];// 16 KB, per-wave, swz ((i&7)<<4)

    const int bh = blockIdx.y;
    const int b = bh >> 3, h = bh & 7;
    const int i0t = blockIdx.x * 16;

    const int tid  = threadIdx.x;
    const int lane = tid & 63, wid = tid >> 6;
    const int ln15 = lane & 15, kgrp = lane >> 4;

    // stage K and V (fp16 straight copies; V transposed)
    for (int u = tid; u < 2048; u += 256) {
        int j = u >> 2, d8 = (u & 3) * 8;
        const size_t src = (size_t)(b * NNq + j) * DDm + h * DHh + d8;
        f16x8 kv = *reinterpret_cast<const f16x8*>(&kk[src]);
        *reinterpret_cast<f16x8*>(reinterpret_cast<char*>(Kh) +
            ((j * 64 + d8 * 2) ^ ((j & 7) << 4))) = kv;
        f16x8 v8 = *reinterpret_cast<const f16x8*>(&vv[src]);
#pragma unroll
        for (int e = 0; e < 8; ++e) {
            int row = d8 + e;
            *reinterpret_cast<_Float16*>(reinterpret_cast<char*>(VT) +
                ((row * 1024 + j * 2) ^ ((row & 7) << 4))) = v8[e];
        }
    }

    // Q-fragment: one 16B load
    f16x8 qf = *reinterpret_cast<const f16x8*>(
        &q[(size_t)(b * NNq + i0t + ln15) * DDm + h * DHh + kgrp * 8]);
    __syncthreads();

    const int jbase = wid * 128;
    const size_t plane = (size_t)NNq * NNq;
    const size_t g_base = (size_t)((l * 8 + h) * BB + b) * plane;

    // QK^T: 8 MFMAs -> lane holds S[i=kgrp*4+r][j=jbase+t*16+ln15]
    f32x4 s[8];
#pragma unroll
    for (int t = 0; t < 8; ++t) {
        int j = jbase + t * 16 + ln15;
        f16x8 kf = *reinterpret_cast<const f16x8*>(reinterpret_cast<char*>(Kh) +
            ((j * 64 + kgrp * 16) ^ ((j & 7) << 4)));
        f32x4 z = {0.f, 0.f, 0.f, 0.f};
        s[t] = __builtin_amdgcn_mfma_f32_16x16x32_f16(qf, kf, z, 0, 0, 0);
    }

    // pre-load G values (independent of the max-reduce -> overlaps it)
    float gv[8][4];
#pragma unroll
    for (int t = 0; t < 8; ++t) {
        const size_t jg = jbase + t * 16 + ln15;
#pragma unroll
        for (int r = 0; r < 4; ++r)
            gv[t][r] = __half2float(G[g_base + (size_t)(i0t + kgrp * 4 + r) * NNq + jg]);
    }

    // one-shot softmax over the wave's 128-j slice: p = G * exp(s*SCALE - m)
    float m_[4], l_[4];
#pragma unroll
    for (int r = 0; r < 4; ++r) {
        float mx = s[0][r];
#pragma unroll
        for (int t = 1; t < 8; ++t) mx = fmaxf(mx, s[t][r]);
        mx *= SCALE;
#pragma unroll
        for (int o = 1; o < 16; o <<= 1) mx = fmaxf(mx, __shfl_xor(mx, o, 64));
        float sum = 0.f;
#pragma unroll
        for (int t = 0; t < 8; ++t) {
            float p = gv[t][r] * __expf(s[t][r] * SCALE - mx);
            s[t][r] = p; sum += p;
        }
#pragma unroll
        for (int o = 1; o < 16; o <<= 1) sum += __shfl_xor(sum, o, 64);
        m_[r] = mx; l_[r] = sum;
    }

    // P -> wave-private LDS (fp16, swizzled); no barrier needed
    {
        char* psb = reinterpret_cast<char*>(Ps[wid]);
#pragma unroll
        for (int r = 0; r < 4; ++r) {
            const int row = kgrp * 4 + r;
            const int rb = row * 256, sw = (row & 7) << 4;
#pragma unroll
            for (int t = 0; t < 8; ++t) {
                int byte = (rb + (t * 16 + ln15) * 2) ^ sw;
                *reinterpret_cast<_Float16*>(psb + byte) = (_Float16)s[t][r];
            }
        }
    }

    // PV: 4 j-chunks x 2 d-tiles
    f32x4 oacc[2] = {{0.f,0.f,0.f,0.f},{0.f,0.f,0.f,0.f}};
    {
        char* psb = reinterpret_cast<char*>(Ps[wid]);
#pragma unroll
        for (int kc = 0; kc < 4; ++kc) {
            f16x8 pf = *reinterpret_cast<const f16x8*>(psb +
                ((ln15 * 256 + kc * 64 + kgrp * 16) ^ ((ln15 & 7) << 4)));
#pragma unroll
            for (int dt = 0; dt < 2; ++dt) {
                int d = dt * 16 + ln15;
                f16x8 vf = *reinterpret_cast<const f16x8*>(reinterpret_cast<char*>(VT) +
                    ((d * 1024 + (jbase + kc * 32 + kgrp * 8) * 2) ^ ((d & 7) << 4)));
                oacc[dt] = __builtin_amdgcn_mfma_f32_16x16x32_f16(pf, vf, oacc[dt], 0, 0, 0);
            }
        }
    }

    // write partials into this wave's (dead) K slab: [16][32] O + m[16] + l[16]
    {
        float* Op = reinterpret_cast<float*>(reinterpret_cast<char*>(Kh) + wid * 8192);
#pragma unroll
        for (int dt = 0; dt < 2; ++dt)
#pragma unroll
            for (int r = 0; r < 4; ++r)
                Op[(kgrp * 4 + r) * 32 + dt * 16 + ln15] = oacc[dt][r];
        if (ln15 == 0) {
#pragma unroll
            for (int r = 0; r < 4; ++r) {
                Op[512 + kgrp * 4 + r] = m_[r];
                Op[528 + kgrp * 4 + r] = l_[r];
            }
        }
    }
    __syncthreads();

    // flash-combine across 4 waves; thread -> (i = tid>>4, d0 = (tid&15)*2)
    {
        const int i = tid >> 4, d0 = (tid & 15) * 2;
        float mw[4], M = -3.0e38f;
#pragma unroll
        for (int w = 0; w < 4; ++w) {
            mw[w] = reinterpret_cast<float*>(reinterpret_cast<char*>(Kh) + w * 8192)[512 + i];
            M = fmaxf(M, mw[w]);
        }
        float o0 = 0.f, o1 = 0.f, ls = 0.f;
#pragma unroll
        for (int w = 0; w < 4; ++w) {
            float* Op = reinterpret_cast<float*>(reinterpret_cast<char*>(Kh) + w * 8192);
            float sc = __expf(mw[w] - M);
            ls += Op[528 + i] * sc;
            o0 += Op[i * 32 + d0] * sc;
            o1 += Op[i * 32 + d0 + 1] * sc;
        }
        float inv = 1.0f / ls;
        f16x2 ov; ov[0] = (_Float16)(o0 * inv); ov[1] = (_Float16)(o1 * inv);
        *reinterpret_cast<f16x2*>(&y[(size_t)(b * NNq + i0t + i) * DDm + h * DHh + d0]) = ov;
    }
}

// ---------------------------------------------------------------- launch
extern "C" void kernel_launch(void* const* d_in, const int* in_sizes, int n_in,
                              void* d_out, int out_size, void* d_ws, size_t ws_size,
                              hipStream_t stream) {
    const float* boxes    = (const float*)d_in[0];
    const float* features = (const float*)d_in[1];
    const int*   mask     = (const int*)d_in[2];
    const float* Wq = (const float*)d_in[3];
    const float* bq = (const float*)d_in[4];
    const float* Wk = (const float*)d_in[5];
    const float* bk = (const float*)d_in[6];
    const float* Wv = (const float*)d_in[7];
    const float* bv = (const float*)d_in[8];
    const float* Wo = (const float*)d_in[9];
    const float* bo = (const float*)d_in[10];
    const float* Wg = (const float*)d_in[11];
    const float* bg = (const float*)d_in[12];
    const float* dv = (const float*)d_in[13];

    char* ws = (char*)d_ws;
    __half*    Gb   = (__half*)(ws);                       // 25,165,824
    _Float16*  WT   = (_Float16*)(ws + 25165824);          //  1,572,864
    _Float16*  WgTg = (_Float16*)(ws + 26738688);          //     16,384
    _Float16*  qb   = (_Float16*)(ws + 26755072);          //    524,288
    _Float16*  kb   = (_Float16*)(ws + 27279360);          //    524,288
    _Float16*  vb   = (_Float16*)(ws + 27803648);          //    524,288
    _Float16*  yb   = (_Float16*)(ws + 28327936);          //    524,288  -> ~28.9 MB
    float*     x    = (float*)d_out;

    k_wcvt<<<dim3(4, 4, 13), dim3(256), 0, stream>>>(Wq, Wk, Wv, Wo, WT, Wg, WgTg);
    k_geo<<<dim3(2048), dim3(256), 0, stream>>>(boxes, WgTg, bg, dv, mask, Gb);

    for (int l = 0; l < LLn; ++l) {
        const _Float16* WTq = WT + (size_t)(l * 4 + 0) * 65536;
        const _Float16* WTk = WT + (size_t)(l * 4 + 1) * 65536;
        const _Float16* WTv = WT + (size_t)(l * 4 + 2) * 65536;
        const _Float16* WTo = WT + (size_t)(l * 4 + 3) * 65536;
        const float* bq_l = bq + (size_t)l * DDm;
        const float* bk_l = bk + (size_t)l * DDm;
        const float* bv_l = bv + (size_t)l * DDm;
        const float* bo_l = bo + (size_t)l * DDm;
        const float* xin  = (l == 0) ? features : x;

        k_gemm_qkv<<<dim3(32, 4, 3), dim3(256), 0, stream>>>(
            xin, WTq, WTk, WTv, bq_l, bk_l, bv_l, qb, kb, vb);
        k_attn<<<dim3(32, 16), dim3(256), 0, stream>>>(qb, kb, vb, Gb, yb, l);
        k_gemm_o<<<dim3(32, 4), dim3(256), 0, stream>>>(
            yb, WTo, bo_l, x, xin);
    }
}

// Round 14
// 99.914 us; speedup vs baseline: 2.5382x; 1.0137x over previous
//
#include <hip/hip_runtime.h>
#include <hip/hip_fp16.h>

// Problem constants (from reference): B=2, N=512, D=256, H=8, L=3
#define BB 2
#define NNq 512
#define DDm 256
#define HHh 8
#define DHh 32
#define LLn 3

static constexpr float EPSF   = 1e-4f;
static constexpr float INV2PI = 0.15915494309189535f;   // 1/(2*pi)
static constexpr float SCALE  = 0.17677669529663687f;   // 1/sqrt(32)

#if __has_builtin(__builtin_amdgcn_fractf)
#define FRACTF(x) __builtin_amdgcn_fractf(x)
#else
#define FRACTF(x) ((x) - floorf(x))
#endif
#if __has_builtin(__builtin_amdgcn_sinf)
#define SINR(x) __builtin_amdgcn_sinf(x)   // sin(2*pi*x), x in revolutions
#define COSR(x) __builtin_amdgcn_cosf(x)
#else
#define SINR(x) __sinf((x) * 6.2831853071795865f)
#define COSR(x) __cosf((x) * 6.2831853071795865f)
#endif
#if __has_builtin(__builtin_amdgcn_rcpf)
#define RCPF(x) __builtin_amdgcn_rcpf(x)
#else
#define RCPF(x) (1.0f / (x))
#endif

typedef _Float16 f16x8 __attribute__((ext_vector_type(8)));
typedef _Float16 f16x4 __attribute__((ext_vector_type(4)));
typedef _Float16 f16x2 __attribute__((ext_vector_type(2)));
typedef float    f32x4 __attribute__((ext_vector_type(4)));

__device__ inline f16x2 pk2(float a, float b) {
#if __has_builtin(__builtin_amdgcn_cvt_pkrtz)
    return __builtin_bit_cast(f16x2, __builtin_amdgcn_cvt_pkrtz(a, b));
#else
    f16x2 r; r[0] = (_Float16)a; r[1] = (_Float16)b; return r;
#endif
}
union U16x8 { f16x8 v; f16x2 h[4]; };

// ---------------------------------------------------------------- weight pre-convert
// z<12: W[l][k][n] fp32 -> WT[(l*4+op)][n][k] fp16 (LDS-bounce transpose).
// z==12 (block 0,0): Wg -> WgTg[32][256] fp16 with the k-XOR swizzle baked.
__global__ __launch_bounds__(256) void k_wcvt(const float* __restrict__ Wq,
        const float* __restrict__ Wk, const float* __restrict__ Wv,
        const float* __restrict__ Wo, _Float16* __restrict__ WT,
        const float* __restrict__ Wg, _Float16* __restrict__ WgTg) {
    __shared__ _Float16 t[64][72];
    const int tid = threadIdx.x;
    const int mat = blockIdx.z;
    if (mat == 12) {
        if (blockIdx.x == 0 && blockIdx.y == 0) {
            for (int idx = tid; idx < 32 * 256; idx += 256) {
                int n = idx >> 8, k = idx & 255;
                float w = (n < 24) ? Wg[(size_t)(n >> 3) * 2048 + (size_t)k * 8 + (n & 7)] : 0.f;
                WgTg[n * 256 + (k ^ ((n & 7) << 3))] = (_Float16)w;
            }
        }
        return;
    }
    const int l = mat >> 2, op = mat & 3;
    const float* W = (op == 0 ? Wq : op == 1 ? Wk : op == 2 ? Wv : Wo)
                     + (size_t)l * 65536;
    const int k0 = blockIdx.x * 64, n0 = blockIdx.y * 64;
    for (int u = tid; u < 64 * 16; u += 256) {
        int k = u >> 4, n4 = (u & 15) * 4;
        float4 w4 = *reinterpret_cast<const float4*>(&W[(size_t)(k0 + k) * 256 + n0 + n4]);
        t[n4 + 0][k] = (_Float16)w4.x; t[n4 + 1][k] = (_Float16)w4.y;
        t[n4 + 2][k] = (_Float16)w4.z; t[n4 + 3][k] = (_Float16)w4.w;
    }
    __syncthreads();
    for (int u = tid; u < 64 * 8; u += 256) {
        int n = u >> 3, kc = (u & 7) * 8;
        *reinterpret_cast<f16x8*>(&WT[((size_t)mat * 256 + n0 + n) * 256 + k0 + kc]) =
            *reinterpret_cast<const f16x8*>(&t[n][kc]);
    }
}

// ---------------------------------------------------------------- fused geo + qkv0
// Blocks 0..2047: geo (round-13 verified structure + fast-rcp rel).
// Blocks 2048..2431: layer-0 qkv GEMM, LDS-FREE: A (features fp32) and W
// (WT fp16) fragments loaded directly global->register (WT rows contiguous:
// 4 kgrp-lanes x 16B = one 64B line per n-row; L2-hot). Independent work ->
// qkv0 rides on CUs idle during geo.
__global__ __launch_bounds__(256, 4) void k_geo_qkv0(const float* __restrict__ boxes,
        const _Float16* __restrict__ WgTg, const float* __restrict__ bg,
        const float* __restrict__ divm, const int* __restrict__ maskp,
        __half* __restrict__ G,
        const float* __restrict__ feat, const _Float16* __restrict__ WT,
        const float* __restrict__ bq, const float* __restrict__ bk,
        const float* __restrict__ bv,
        _Float16* __restrict__ qb, _Float16* __restrict__ kb,
        _Float16* __restrict__ vb) {
    __shared__ __half obuf[4][24][68];   // geo part only (13 KB)

    const int tid  = threadIdx.x;
    const int lane = tid & 63;
    const int wid  = tid >> 6;
    const int ln15 = lane & 15;
    const int kgrp = lane >> 4;

    if ((int)blockIdx.x >= 2048) {
        // ---------------- qkv layer-0 (LDS-free) ----------------
        const int q = blockIdx.x - 2048;         // 0..383
        const int z = q >> 7;                    // 0..2
        const int rem = q & 127;
        const int m0 = (rem >> 2) * 32, n0 = (rem & 3) * 64;
        const _Float16* WTz = WT + (size_t)z * 65536;   // layer-0 ops are mats 0..2
        const float* bia = (z == 0) ? bq : (z == 1) ? bk : bv;
        _Float16* C = (z == 0) ? qb : (z == 1) ? kb : vb;

        const int mw   = (wid & 1) * 16;
        const int nsel = (wid >> 1) * 16;
        const int kfr  = kgrp * 8;

        const float* Arow = feat + (size_t)(m0 + mw + ln15) * 256;
        const _Float16* W0r = WTz + (size_t)(n0 + nsel + ln15) * 256;
        const _Float16* W1r = WTz + (size_t)(n0 + nsel + 32 + ln15) * 256;

        f32x4 acc[2] = {{0.f,0.f,0.f,0.f},{0.f,0.f,0.f,0.f}};
#pragma unroll
        for (int kc = 0; kc < 8; ++kc) {
            float4 a0 = *reinterpret_cast<const float4*>(Arow + kc * 32 + kfr);
            float4 a1 = *reinterpret_cast<const float4*>(Arow + kc * 32 + kfr + 4);
            U16x8 af;
            af.h[0] = pk2(a0.x, a0.y); af.h[1] = pk2(a0.z, a0.w);
            af.h[2] = pk2(a1.x, a1.y); af.h[3] = pk2(a1.z, a1.w);
            f16x8 b0 = *reinterpret_cast<const f16x8*>(W0r + kc * 32 + kfr);
            f16x8 b1 = *reinterpret_cast<const f16x8*>(W1r + kc * 32 + kfr);
            acc[0] = __builtin_amdgcn_mfma_f32_16x16x32_f16(af.v, b0, acc[0], 0, 0, 0);
            acc[1] = __builtin_amdgcn_mfma_f32_16x16x32_f16(af.v, b1, acc[1], 0, 0, 0);
        }
#pragma unroll
        for (int t = 0; t < 2; ++t) {
            const int col = n0 + nsel + t * 32 + ln15;
            const float bv_ = bia[col];
#pragma unroll
            for (int r = 0; r < 4; ++r) {
                const int row = m0 + mw + kgrp * 4 + r;
                C[(size_t)row * 256 + col] = (_Float16)fmaxf(acc[t][r] + bv_, 0.f);
            }
        }
        return;
    }

    // ---------------- geo ----------------
    float invd[8];
    {
        const float4* dv4 = reinterpret_cast<const float4*>(divm);
        float4 da = dv4[kgrp * 2], db = dv4[kgrp * 2 + 1];
        invd[0] = INV2PI / da.x; invd[1] = INV2PI / da.y;
        invd[2] = INV2PI / da.z; invd[3] = INV2PI / da.w;
        invd[4] = INV2PI / db.x; invd[5] = INV2PI / db.y;
        invd[6] = INV2PI / db.z; invd[7] = INV2PI / db.w;
    }
    const int n0 = ln15;
    const int n1 = 16 + ln15;
    const float bg0 = bg[n0];
    const float bg1 = (n1 < 24) ? bg[n1] : 0.f;

    const int mask  = (ln15 & 7) << 3;
    const int flip5 = mask & 32;
    const int kb_   = (kgrp << 3) ^ (mask & 24);
    const int base0 = n0 * 256 + kb_;
    const int base1 = n1 * 256 + kb_;

    f16x8 bS0[4], bC0[4], bS1[4], bC1[4];
#pragma unroll
    for (int kc2 = 0; kc2 < 4; ++kc2) {
        const int koffS = ((2 * kc2) * 32) ^ flip5;
        const int koffC = ((2 * kc2 + 1) * 32) ^ flip5;
        bS0[kc2] = *reinterpret_cast<const f16x8*>(&WgTg[base0 + koffS]);
        bC0[kc2] = *reinterpret_cast<const f16x8*>(&WgTg[base0 + koffC]);
        bS1[kc2] = *reinterpret_cast<const f16x8*>(&WgTg[base1 + koffS]);
        bC1[kc2] = *reinterpret_cast<const f16x8*>(&WgTg[base1 + koffC]);
    }

    const float4* boxes4 = reinterpret_cast<const float4*>(boxes);
    const size_t plane = (size_t)NNq * NNq;

    const int base4 = (blockIdx.x * 4 + wid) * 4;
#pragma unroll
    for (int it = 0; it < 4; ++it) {
        const int slab = base4 + it;
        const int p0 = slab << 4;
        const int b  = p0 >> 18;
        const int rem = p0 & (NNq * NNq - 1);
        const int i  = rem >> 9;
        const int j0 = rem & (NNq - 1);

        float4 Bi = boxes4[b * NNq + i];
        float4 Bj = boxes4[b * NNq + j0 + ln15];
        float cxi = 0.5f * (Bi.x + Bi.z), cyi = 0.5f * (Bi.y + Bi.w);
        float wi  = fmaxf(Bi.z - Bi.x, EPSF), hi = fmaxf(Bi.w - Bi.y, EPSF);
        float cxj = 0.5f * (Bj.x + Bj.z), cyj = 0.5f * (Bj.y + Bj.w);
        float wj  = fmaxf(Bj.z - Bj.x, EPSF), hj = fmaxf(Bj.w - Bj.y, EPSF);
        float rwj = RCPF(wj), rhj = RCPF(hj);
        float rel[4];
        rel[0] = __logf(fabsf(cxj - cxi) * rwj + EPSF);
        rel[1] = __logf(fabsf(cyj - cyi) * rhj + EPSF);
        rel[2] = __logf(wi * rwj + EPSF);
        rel[3] = __logf(hi * rhj + EPSF);

        f32x4 acc0 = {0.f, 0.f, 0.f, 0.f};
        f32x4 acc1 = {0.f, 0.f, 0.f, 0.f};

#pragma unroll
        for (int kc2 = 0; kc2 < 4; ++kc2) {
            const float rc = rel[kc2];
            U16x8 afs, afc;
#pragma unroll
            for (int jj = 0; jj < 4; ++jj) {
                float rv0 = FRACTF(rc * invd[2 * jj]);
                float rv1 = FRACTF(rc * invd[2 * jj + 1]);
                afs.h[jj] = pk2(SINR(rv0), SINR(rv1));
                afc.h[jj] = pk2(COSR(rv0), COSR(rv1));
            }
            acc0 = __builtin_amdgcn_mfma_f32_16x16x32_f16(afs.v, bS0[kc2], acc0, 0, 0, 0);
            acc0 = __builtin_amdgcn_mfma_f32_16x16x32_f16(afc.v, bC0[kc2], acc0, 0, 0, 0);
            acc1 = __builtin_amdgcn_mfma_f32_16x16x32_f16(afs.v, bS1[kc2], acc1, 0, 0, 0);
            acc1 = __builtin_amdgcn_mfma_f32_16x16x32_f16(afc.v, bC1[kc2], acc1, 0, 0, 0);
        }

#pragma unroll
        for (int r = 0; r < 4; ++r) {
            const int m = it * 16 + (kgrp << 2) + r;
            float g0 = fmaxf(acc0[r] + bg0, 0.f);
            obuf[wid][n0][m] = __float2half(g0);
            if (n1 < 24) {
                float g1 = fmaxf(acc1[r] + bg1, 0.f);
                obuf[wid][n1][m] = __float2half(g1);
            }
        }
    }
    __syncthreads();

    const int b_  = base4 >> 14;
    const int i_  = (base4 >> 5) & (NNq - 1);
    const int j0b = (base4 & 31) << 4;
    const int mv  = maskp[((size_t)b_ * NNq + i_) * NNq + j0b + lane];
    size_t obase = (size_t)b_ * plane + (size_t)i_ * NNq + j0b + lane;
#pragma unroll
    for (int t = 0; t < 24; ++t) {
        float g = __half2float(obuf[wid][t][lane]);
        float v = (mv != 0) ? (g + 1e-6f) : 0.0f;
        G[obase + (size_t)t * (BB * plane)] = __float2half(v);
    }
}

// ---------------------------------------------------------------- GEMM qkv (fp16 A, LDS-free)
__global__ __launch_bounds__(256) void k_gemm_qkv_h(const _Float16* __restrict__ A,
        const _Float16* __restrict__ WT0, const _Float16* __restrict__ WT1,
        const _Float16* __restrict__ WT2,
        const float* __restrict__ b0, const float* __restrict__ b1, const float* __restrict__ b2,
        _Float16* __restrict__ C0, _Float16* __restrict__ C1, _Float16* __restrict__ C2) {
    const _Float16* WTz = (blockIdx.z == 0) ? WT0 : (blockIdx.z == 1) ? WT1 : WT2;
    const float*    bia = (blockIdx.z == 0) ? b0 : (blockIdx.z == 1) ? b1 : b2;
    _Float16*       C   = (blockIdx.z == 0) ? C0 : (blockIdx.z == 1) ? C1 : C2;

    const int tid  = threadIdx.x;
    const int lane = tid & 63, wid = tid >> 6;
    const int ln15 = lane & 15, kgrp = lane >> 4;
    const int m0 = blockIdx.x * 32, n0 = blockIdx.y * 64;
    const int mw   = (wid & 1) * 16;
    const int nsel = (wid >> 1) * 16;
    const int kfr  = kgrp * 8;

    const _Float16* Arow = A + (size_t)(m0 + mw + ln15) * 256;
    const _Float16* W0r  = WTz + (size_t)(n0 + nsel + ln15) * 256;
    const _Float16* W1r  = WTz + (size_t)(n0 + nsel + 32 + ln15) * 256;

    f32x4 acc[2] = {{0.f,0.f,0.f,0.f},{0.f,0.f,0.f,0.f}};
#pragma unroll
    for (int kc = 0; kc < 8; ++kc) {
        f16x8 af = *reinterpret_cast<const f16x8*>(Arow + kc * 32 + kfr);
        f16x8 b0_ = *reinterpret_cast<const f16x8*>(W0r + kc * 32 + kfr);
        f16x8 b1_ = *reinterpret_cast<const f16x8*>(W1r + kc * 32 + kfr);
        acc[0] = __builtin_amdgcn_mfma_f32_16x16x32_f16(af, b0_, acc[0], 0, 0, 0);
        acc[1] = __builtin_amdgcn_mfma_f32_16x16x32_f16(af, b1_, acc[1], 0, 0, 0);
    }
#pragma unroll
    for (int t = 0; t < 2; ++t) {
        const int col = n0 + nsel + t * 32 + ln15;
        const float bv = bia[col];
#pragma unroll
        for (int r = 0; r < 4; ++r) {
            const int row = m0 + mw + kgrp * 4 + r;
            C[(size_t)row * 256 + col] = (_Float16)fmaxf(acc[t][r] + bv, 0.f);
        }
    }
}

// ---------------------------------------------------------------- GEMM o (LDS-free; dual fp32+fp16 out)
__global__ __launch_bounds__(256) void k_gemm_o(const _Float16* __restrict__ A,
        const _Float16* __restrict__ WT0, const float* __restrict__ bia,
        float* __restrict__ C, _Float16* __restrict__ Ch,
        const float* __restrict__ resid) {
    const int tid  = threadIdx.x;
    const int lane = tid & 63, wid = tid >> 6;
    const int ln15 = lane & 15, kgrp = lane >> 4;
    const int m0 = blockIdx.x * 32, n0 = blockIdx.y * 64;
    const int mw   = (wid & 1) * 16;
    const int nsel = (wid >> 1) * 16;
    const int kfr  = kgrp * 8;

    const _Float16* Arow = A + (size_t)(m0 + mw + ln15) * 256;
    const _Float16* W0r  = WT0 + (size_t)(n0 + nsel + ln15) * 256;
    const _Float16* W1r  = WT0 + (size_t)(n0 + nsel + 32 + ln15) * 256;

    f32x4 acc[2] = {{0.f,0.f,0.f,0.f},{0.f,0.f,0.f,0.f}};
#pragma unroll
    for (int kc = 0; kc < 8; ++kc) {
        f16x8 af = *reinterpret_cast<const f16x8*>(Arow + kc * 32 + kfr);
        f16x8 b0_ = *reinterpret_cast<const f16x8*>(W0r + kc * 32 + kfr);
        f16x8 b1_ = *reinterpret_cast<const f16x8*>(W1r + kc * 32 + kfr);
        acc[0] = __builtin_amdgcn_mfma_f32_16x16x32_f16(af, b0_, acc[0], 0, 0, 0);
        acc[1] = __builtin_amdgcn_mfma_f32_16x16x32_f16(af, b1_, acc[1], 0, 0, 0);
    }
#pragma unroll
    for (int t = 0; t < 2; ++t) {
        const int col = n0 + nsel + t * 32 + ln15;
        const float bv = bia[col];
#pragma unroll
        for (int r = 0; r < 4; ++r) {
            const int row = m0 + mw + kgrp * 4 + r;
            float o = fmaxf(acc[t][r] + bv, 0.f) + resid[(size_t)row * 256 + col];
            C[(size_t)row * 256 + col] = o;
            Ch[(size_t)row * 256 + col] = (_Float16)o;
        }
    }
}

// ---------------------------------------------------------------- fused attention (MFMA v2, multiplicative geo)
__global__ __launch_bounds__(256) void k_attn(const _Float16* __restrict__ q,
                                              const _Float16* __restrict__ kk,
                                              const _Float16* __restrict__ vv,
                                              const __half* __restrict__ G,
                                              _Float16* __restrict__ y, int l) {
    __shared__ _Float16 Kh[512 * 32];   // 32 KB, row j: 64B, swz ((j&7)<<4)
    __shared__ _Float16 VT[32 * 512];   // 32 KB, row d: 1KB, swz ((d&7)<<4)
    __shared__ _Float16 Ps[4][16 * 128];// 16 KB, per-wave, swz ((i&7)<<4)

    const int bh = blockIdx.y;
    const int b = bh >> 3, h = bh & 7;
    const int i0t = blockIdx.x * 16;

    const int tid  = threadIdx.x;
    const int lane = tid & 63, wid = tid >> 6;
    const int ln15 = lane & 15, kgrp = lane >> 4;

    for (int u = tid; u < 2048; u += 256) {
        int j = u >> 2, d8 = (u & 3) * 8;
        const size_t src = (size_t)(b * NNq + j) * DDm + h * DHh + d8;
        f16x8 kv = *reinterpret_cast<const f16x8*>(&kk[src]);
        *reinterpret_cast<f16x8*>(reinterpret_cast<char*>(Kh) +
            ((j * 64 + d8 * 2) ^ ((j & 7) << 4))) = kv;
        f16x8 v8 = *reinterpret_cast<const f16x8*>(&vv[src]);
#pragma unroll
        for (int e = 0; e < 8; ++e) {
            int row = d8 + e;
            *reinterpret_cast<_Float16*>(reinterpret_cast<char*>(VT) +
                ((row * 1024 + j * 2) ^ ((row & 7) << 4))) = v8[e];
        }
    }

    f16x8 qf = *reinterpret_cast<const f16x8*>(
        &q[(size_t)(b * NNq + i0t + ln15) * DDm + h * DHh + kgrp * 8]);
    __syncthreads();

    const int jbase = wid * 128;
    const size_t plane = (size_t)NNq * NNq;
    const size_t g_base = (size_t)((l * 8 + h) * BB + b) * plane;

    f32x4 s[8];
#pragma unroll
    for (int t = 0; t < 8; ++t) {
        int j = jbase + t * 16 + ln15;
        f16x8 kf = *reinterpret_cast<const f16x8*>(reinterpret_cast<char*>(Kh) +
            ((j * 64 + kgrp * 16) ^ ((j & 7) << 4)));
        f32x4 z = {0.f, 0.f, 0.f, 0.f};
        s[t] = __builtin_amdgcn_mfma_f32_16x16x32_f16(qf, kf, z, 0, 0, 0);
    }

    float gv[8][4];
#pragma unroll
    for (int t = 0; t < 8; ++t) {
        const size_t jg = jbase + t * 16 + ln15;
#pragma unroll
        for (int r = 0; r < 4; ++r)
            gv[t][r] = __half2float(G[g_base + (size_t)(i0t + kgrp * 4 + r) * NNq + jg]);
    }

    float m_[4], l_[4];
#pragma unroll
    for (int r = 0; r < 4; ++r) {
        float mx = s[0][r];
#pragma unroll
        for (int t = 1; t < 8; ++t) mx = fmaxf(mx, s[t][r]);
        mx *= SCALE;
#pragma unroll
        for (int o = 1; o < 16; o <<= 1) mx = fmaxf(mx, __shfl_xor(mx, o, 64));
        float sum = 0.f;
#pragma unroll
        for (int t = 0; t < 8; ++t) {
            float p = gv[t][r] * __expf(s[t][r] * SCALE - mx);
            s[t][r] = p; sum += p;
        }
#pragma unroll
        for (int o = 1; o < 16; o <<= 1) sum += __shfl_xor(sum, o, 64);
        m_[r] = mx; l_[r] = sum;
    }

    {
        char* psb = reinterpret_cast<char*>(Ps[wid]);
#pragma unroll
        for (int r = 0; r < 4; ++r) {
            const int row = kgrp * 4 + r;
            const int rb = row * 256, sw = (row & 7) << 4;
#pragma unroll
            for (int t = 0; t < 8; ++t) {
                int byte = (rb + (t * 16 + ln15) * 2) ^ sw;
                *reinterpret_cast<_Float16*>(psb + byte) = (_Float16)s[t][r];
            }
        }
    }

    f32x4 oacc[2] = {{0.f,0.f,0.f,0.f},{0.f,0.f,0.f,0.f}};
    {
        char* psb = reinterpret_cast<char*>(Ps[wid]);
#pragma unroll
        for (int kc = 0; kc < 4; ++kc) {
            f16x8 pf = *reinterpret_cast<const f16x8*>(psb +
                ((ln15 * 256 + kc * 64 + kgrp * 16) ^ ((ln15 & 7) << 4)));
#pragma unroll
            for (int dt = 0; dt < 2; ++dt) {
                int d = dt * 16 + ln15;
                f16x8 vf = *reinterpret_cast<const f16x8*>(reinterpret_cast<char*>(VT) +
                    ((d * 1024 + (jbase + kc * 32 + kgrp * 8) * 2) ^ ((d & 7) << 4)));
                oacc[dt] = __builtin_amdgcn_mfma_f32_16x16x32_f16(pf, vf, oacc[dt], 0, 0, 0);
            }
        }
    }

    {
        float* Op = reinterpret_cast<float*>(reinterpret_cast<char*>(Kh) + wid * 8192);
#pragma unroll
        for (int dt = 0; dt < 2; ++dt)
#pragma unroll
            for (int r = 0; r < 4; ++r)
                Op[(kgrp * 4 + r) * 32 + dt * 16 + ln15] = oacc[dt][r];
        if (ln15 == 0) {
#pragma unroll
            for (int r = 0; r < 4; ++r) {
                Op[512 + kgrp * 4 + r] = m_[r];
                Op[528 + kgrp * 4 + r] = l_[r];
            }
        }
    }
    __syncthreads();

    {
        const int i = tid >> 4, d0 = (tid & 15) * 2;
        float mw[4], M = -3.0e38f;
#pragma unroll
        for (int w = 0; w < 4; ++w) {
            mw[w] = reinterpret_cast<float*>(reinterpret_cast<char*>(Kh) + w * 8192)[512 + i];
            M = fmaxf(M, mw[w]);
        }
        float o0 = 0.f, o1 = 0.f, ls = 0.f;
#pragma unroll
        for (int w = 0; w < 4; ++w) {
            float* Op = reinterpret_cast<float*>(reinterpret_cast<char*>(Kh) + w * 8192);
            float sc = __expf(mw[w] - M);
            ls += Op[528 + i] * sc;
            o0 += Op[i * 32 + d0] * sc;
            o1 += Op[i * 32 + d0 + 1] * sc;
        }
        float inv = 1.0f / ls;
        f16x2 ov; ov[0] = (_Float16)(o0 * inv); ov[1] = (_Float16)(o1 * inv);
        *reinterpret_cast<f16x2*>(&y[(size_t)(b * NNq + i0t + i) * DDm + h * DHh + d0]) = ov;
    }
}

// ---------------------------------------------------------------- launch
extern "C" void kernel_launch(void* const* d_in, const int* in_sizes, int n_in,
                              void* d_out, int out_size, void* d_ws, size_t ws_size,
                              hipStream_t stream) {
    const float* boxes    = (const float*)d_in[0];
    const float* features = (const float*)d_in[1];
    const int*   mask     = (const int*)d_in[2];
    const float* Wq = (const float*)d_in[3];
    const float* bq = (const float*)d_in[4];
    const float* Wk = (const float*)d_in[5];
    const float* bk = (const float*)d_in[6];
    const float* Wv = (const float*)d_in[7];
    const float* bv = (const float*)d_in[8];
    const float* Wo = (const float*)d_in[9];
    const float* bo = (const float*)d_in[10];
    const float* Wg = (const float*)d_in[11];
    const float* bg = (const float*)d_in[12];
    const float* dv = (const float*)d_in[13];

    char* ws = (char*)d_ws;
    __half*    Gb   = (__half*)(ws);                       // 25,165,824
    _Float16*  WT   = (_Float16*)(ws + 25165824);          //  1,572,864
    _Float16*  WgTg = (_Float16*)(ws + 26738688);          //     16,384
    _Float16*  qb   = (_Float16*)(ws + 26755072);          //    524,288
    _Float16*  kb   = (_Float16*)(ws + 27279360);          //    524,288
    _Float16*  vb   = (_Float16*)(ws + 27803648);          //    524,288
    _Float16*  yb   = (_Float16*)(ws + 28327936);          //    524,288
    _Float16*  xh   = (_Float16*)(ws + 28852224);          //    524,288  -> ~29.4 MB
    float*     x    = (float*)d_out;

    k_wcvt<<<dim3(4, 4, 13), dim3(256), 0, stream>>>(Wq, Wk, Wv, Wo, WT, Wg, WgTg);
    k_geo_qkv0<<<dim3(2432), dim3(256), 0, stream>>>(
        boxes, WgTg, bg, dv, mask, Gb,
        features, WT, bq, bk, bv, qb, kb, vb);

    for (int l = 0; l < LLn; ++l) {
        const _Float16* WTq = WT + (size_t)(l * 4 + 0) * 65536;
        const _Float16* WTk = WT + (size_t)(l * 4 + 1) * 65536;
        const _Float16* WTv = WT + (size_t)(l * 4 + 2) * 65536;
        const _Float16* WTo = WT + (size_t)(l * 4 + 3) * 65536;
        const float* bq_l = bq + (size_t)l * DDm;
        const float* bk_l = bk + (size_t)l * DDm;
        const float* bv_l = bv + (size_t)l * DDm;
        const float* bo_l = bo + (size_t)l * DDm;

        if (l > 0) {
            k_gemm_qkv_h<<<dim3(32, 4, 3), dim3(256), 0, stream>>>(
                xh, WTq, WTk, WTv, bq_l, bk_l, bv_l, qb, kb, vb);
        }
        k_attn<<<dim3(32, 16), dim3(256), 0, stream>>>(qb, kb, vb, Gb, yb, l);
        if (l == 0) {
            // resid = features (fp32)
            k_gemm_o<<<dim3(32, 4), dim3(256), 0, stream>>>(
                yb, WTo, bo_l, x, xh, features);
        } else {
            k_gemm_o<<<dim3(32, 4), dim3(256), 0, stream>>>(
                yb, WTo, bo_l, x, xh, x);
        }
    }
}